// Round 4
// baseline (25026.320 us; speedup 1.0000x reference)
//
#include <hip/hip_runtime.h>
#include <hip/hip_bf16.h>

#define TT   2048
#define NN   11
#define EE   110
#define NFD  5
#define EFD  4
#define HIDD 256
#define EEDD 32
#define DD1  256
#define G3   768
#define HPAD 264   // bf16 row stride for h in LDS

typedef __attribute__((ext_vector_type(8))) short short8v;
typedef __attribute__((ext_vector_type(4))) float float4v;

static __device__ inline short f2bf(float f) {
    union { __hip_bfloat16 b; short s; } u; u.b = __float2bfloat16(f); return u.s;
}
static __device__ inline float bf2f(short s) {
    union { short s; __hip_bfloat16 b; } u; u.s = s; return __bfloat162float(u.b);
}
static __device__ inline float sigm_f(float x) {
    return __builtin_amdgcn_rcpf(1.f + __builtin_amdgcn_exp2f(-1.4426950408889634f * x));
}
static __device__ inline float tanh_f(float x) {
    float e = __builtin_amdgcn_exp2f(2.8853900817779268f * x);   // exp(2x)
    return 1.f - 2.f * __builtin_amdgcn_rcpf(e + 1.f);
}
static __device__ inline void gld16(const float* g, float* s) {
    __builtin_amdgcn_global_load_lds((const __attribute__((address_space(1))) void*)g,
                                     (__attribute__((address_space(3))) void*)s, 16, 0, 0);
}

// ---------------------------------------------------------------------------
// Kernel A: time-parallel precompute. One block per timestep t.
// ---------------------------------------------------------------------------
__global__ __launch_bounds__(256) void precompute_kernel(
    const float* __restrict__ x, const float* __restrict__ edge_attr,
    const float* __restrict__ evs, const int* __restrict__ eidx,
    const float* __restrict__ W_np, const float* __restrict__ b_np,
    const float* __restrict__ bn_g, const float* __restrict__ bn_b,
    const float* __restrict__ We1, const float* __restrict__ be1,
    const float* __restrict__ We2, const float* __restrict__ be2,
    const float* __restrict__ Wg1, const float* __restrict__ bg1,
    const float* __restrict__ Wa1, const float* __restrict__ ba1,
    const float* __restrict__ Wg2, const float* __restrict__ bg2,
    const float* __restrict__ Wa2, const float* __restrict__ ba2,
    const float* __restrict__ ln_g, const float* __restrict__ ln_b,
    const float* __restrict__ W_ih, const float* __restrict__ b_ih,
    const float* __restrict__ Wf, const float* __restrict__ bf_,
    float* __restrict__ gi_out, float* __restrict__ evc_out)
{
    const int t   = blockIdx.x;
    const int tid = threadIdx.x;

    __shared__ __align__(16) float sh_h[NN][64];
    __shared__ __align__(16) float sh_e1[EE][32];
    __shared__ __align__(16) float sh_ea[EE][16];
    __shared__ __align__(16) float sh_h1[NN][DD1];
    __shared__ __align__(16) float sh_x[NN][DD1];
    __shared__ float sxt[NN * NFD];
    __shared__ float sev[EEDD];
    __shared__ float seat[EE * EFD];
    __shared__ float red[356];
    __shared__ float sh_s1[NN], sh_d1[NN];
    __shared__ float sh_elog[EE], sh_logit[EE], sh_alpha[EE];
    __shared__ float sh_mu[NN], sh_rs[NN];
    __shared__ float sredv[2];
    __shared__ int s_src[EE], s_dst[EE];
    __shared__ int cnt[NN], deg_start[NN + 1], e_by_dst[EE];

    if (tid < NN * NFD) sxt[tid] = x[(size_t)t * NN * NFD + tid];
    if (tid < EEDD)     sev[tid] = evs[(size_t)t * EEDD + tid];
    for (int i = tid; i < EE * EFD; i += 256)
        seat[i] = edge_attr[(size_t)t * EE * EFD + i];
    if (tid < EE) { s_src[tid] = eidx[tid]; s_dst[tid] = eidx[EE + tid]; }
    if (tid < NN) cnt[tid] = 0;
    __syncthreads();
    if (tid < EE) atomicAdd(&cnt[s_dst[tid]], 1);
    __syncthreads();
    if (tid == 0) {
        int a = 0;
        for (int n = 0; n < NN; n++) { deg_start[n] = a; a += cnt[n]; }
        deg_start[NN] = a;
    }
    __syncthreads();
    if (tid < NN) cnt[tid] = 0;
    __syncthreads();
    if (tid < EE) {
        int d = s_dst[tid];
        int pos = deg_start[d] + atomicAdd(&cnt[d], 1);
        e_by_dst[pos] = tid;
    }

    const float bn_inv = 1.0f / sqrtf(1.0f + 1e-5f);
    __syncthreads();
    for (int i = tid; i < NN * 64; i += 256) {
        int n = i >> 6, d = i & 63;
        float a = b_np[d];
        #pragma unroll
        for (int k = 0; k < NFD; k++) a += sxt[n * NFD + k] * W_np[k * 64 + d];
        a = fmaxf(a, 0.f);
        sh_h[n][d] = bn_g[d] * (a * bn_inv) + bn_b[d];
    }
    __syncthreads();

    for (int i = tid; i < EE * 32; i += 256) {
        int e = i >> 5, d = i & 31;
        float a = be1[d];
        #pragma unroll
        for (int k = 0; k < EFD; k++) a += seat[e * EFD + k] * We1[k * 32 + d];
        sh_e1[e][d] = fmaxf(a, 0.f);
    }
    __syncthreads();
    for (int i = tid; i < EE * 16; i += 256) {
        int e = i >> 4, d = i & 15;
        float a = be2[d];
        #pragma unroll
        for (int k = 0; k < 32; k++) a += sh_e1[e][k] * We2[k * 16 + d];
        sh_ea[e][d] = fmaxf(a, 0.f);
    }
    __syncthreads();

    // ======================= GAT layer 1 ====================================
    {
        const int j = tid;
        float acc[NN];
        #pragma unroll
        for (int n = 0; n < NN; n++) acc[n] = bg1[j];
        for (int k = 0; k < 64; k += 4) {
            float w0 = Wg1[(k + 0) * DD1 + j], w1 = Wg1[(k + 1) * DD1 + j];
            float w2 = Wg1[(k + 2) * DD1 + j], w3 = Wg1[(k + 3) * DD1 + j];
            #pragma unroll
            for (int n = 0; n < NN; n++) {
                float4 hv = *(const float4*)&sh_h[n][k];
                acc[n] = fmaf(hv.w, w3, fmaf(hv.z, w2, fmaf(hv.y, w1, fmaf(hv.x, w0, acc[n]))));
            }
        }
        #pragma unroll
        for (int n = 0; n < NN; n++) sh_h1[n][j] = acc[n];
    }
    __syncthreads();
    if (tid < EE) {
        float a = ba1[0];
        #pragma unroll
        for (int k = 0; k < 16; k++) a += sh_ea[tid][k] * Wa1[2 * DD1 + k];
        sh_elog[tid] = a;
    }
    if (tid < 176) {
        int g = tid >> 3, jj = tid & 7;
        int n = (g < NN) ? g : (g - NN);
        const float* wa = (g < NN) ? Wa1 : (Wa1 + DD1);
        float s = 0.f;
        for (int k = jj; k < DD1; k += 8) s += sh_h1[n][k] * wa[k];
        red[tid] = s;
    }
    __syncthreads();
    if (tid < 22) {
        float s = 0.f;
        #pragma unroll
        for (int j2 = 0; j2 < 8; j2++) s += red[tid * 8 + j2];
        if (tid < NN) sh_s1[tid] = s; else sh_d1[tid - NN] = s;
    }
    __syncthreads();
    if (tid < EE) sh_logit[tid] = sh_s1[s_src[tid]] + sh_d1[s_dst[tid]] + sh_elog[tid];
    __syncthreads();
    if (tid < 128) red[tid] = (tid < EE) ? sh_logit[tid] : -3.0e38f;
    __syncthreads();
    for (int s = 64; s > 0; s >>= 1) {
        if (tid < s) red[tid] = fmaxf(red[tid], red[tid + s]);
        __syncthreads();
    }
    if (tid == 0) sredv[0] = red[0];
    __syncthreads();
    if (tid < 128) {
        float v = (tid < EE) ? expf(sh_logit[tid] - sredv[0]) : 0.f;
        if (tid < EE) sh_alpha[tid] = v;
        red[tid] = v;
    }
    __syncthreads();
    for (int s = 64; s > 0; s >>= 1) {
        if (tid < s) red[tid] += red[tid + s];
        __syncthreads();
    }
    if (tid == 0) sredv[1] = 1.f / red[0];
    __syncthreads();
    if (tid < EE) sh_alpha[tid] *= sredv[1];
    __syncthreads();
    for (int i = tid; i < NN * DD1; i += 256) {
        int n = i >> 8, d = i & 255;
        float a = 0.f;
        for (int p = deg_start[n]; p < deg_start[n + 1]; p++) {
            int e = e_by_dst[p];
            a += sh_alpha[e] * sh_h1[s_src[e]][d];
        }
        sh_x[n][d] = fmaxf(a, 0.f);
    }
    __syncthreads();

    // ======================= GAT layer 2 ====================================
    {
        const int j = tid;
        float acc[NN];
        #pragma unroll
        for (int n = 0; n < NN; n++) acc[n] = bg2[j];
        for (int k = 0; k < DD1; k += 4) {
            float w0 = Wg2[(k + 0) * DD1 + j], w1 = Wg2[(k + 1) * DD1 + j];
            float w2 = Wg2[(k + 2) * DD1 + j], w3 = Wg2[(k + 3) * DD1 + j];
            #pragma unroll
            for (int n = 0; n < NN; n++) {
                float4 xv = *(const float4*)&sh_x[n][k];
                acc[n] = fmaf(xv.w, w3, fmaf(xv.z, w2, fmaf(xv.y, w1, fmaf(xv.x, w0, acc[n]))));
            }
        }
        #pragma unroll
        for (int n = 0; n < NN; n++) sh_h1[n][j] = acc[n];
    }
    __syncthreads();
    if (tid < EE) {
        float a = ba2[0];
        #pragma unroll
        for (int k = 0; k < 16; k++) a += sh_ea[tid][k] * Wa2[2 * DD1 + k];
        sh_elog[tid] = a;
    }
    if (tid < 176) {
        int g = tid >> 3, jj = tid & 7;
        int n = (g < NN) ? g : (g - NN);
        const float* wa = (g < NN) ? Wa2 : (Wa2 + DD1);
        float s = 0.f;
        for (int k = jj; k < DD1; k += 8) s += sh_h1[n][k] * wa[k];
        red[tid] = s;
    }
    __syncthreads();
    if (tid < 22) {
        float s = 0.f;
        #pragma unroll
        for (int j2 = 0; j2 < 8; j2++) s += red[tid * 8 + j2];
        if (tid < NN) sh_s1[tid] = s; else sh_d1[tid - NN] = s;
    }
    __syncthreads();
    if (tid < EE) sh_logit[tid] = sh_s1[s_src[tid]] + sh_d1[s_dst[tid]] + sh_elog[tid];
    __syncthreads();
    if (tid < 128) red[tid] = (tid < EE) ? sh_logit[tid] : -3.0e38f;
    __syncthreads();
    for (int s = 64; s > 0; s >>= 1) {
        if (tid < s) red[tid] = fmaxf(red[tid], red[tid + s]);
        __syncthreads();
    }
    if (tid == 0) sredv[0] = red[0];
    __syncthreads();
    if (tid < 128) {
        float v = (tid < EE) ? expf(sh_logit[tid] - sredv[0]) : 0.f;
        if (tid < EE) sh_alpha[tid] = v;
        red[tid] = v;
    }
    __syncthreads();
    for (int s = 64; s > 0; s >>= 1) {
        if (tid < s) red[tid] += red[tid + s];
        __syncthreads();
    }
    if (tid == 0) sredv[1] = 1.f / red[0];
    __syncthreads();
    if (tid < EE) sh_alpha[tid] *= sredv[1];
    __syncthreads();
    for (int i = tid; i < NN * DD1; i += 256) {
        int n = i >> 8, d = i & 255;
        float a = 0.f;
        for (int p = deg_start[n]; p < deg_start[n + 1]; p++) {
            int e = e_by_dst[p];
            a += sh_alpha[e] * sh_h1[s_src[e]][d];
        }
        sh_x[n][d] = fmaxf(a, 0.f);
    }
    __syncthreads();

    // ---- LayerNorm ---------------------------------------------------------
    if (tid < 176) {
        int n = tid >> 4, jj = tid & 15;
        float s = 0.f, q = 0.f;
        for (int k = jj; k < DD1; k += 16) {
            float v = sh_x[n][k];
            s += v; q += v * v;
        }
        red[tid] = s; red[176 + tid] = q;
    }
    __syncthreads();
    if (tid < NN) {
        float s = 0.f, q = 0.f;
        #pragma unroll
        for (int j2 = 0; j2 < 16; j2++) { s += red[tid * 16 + j2]; q += red[176 + tid * 16 + j2]; }
        float mu = s * (1.f / 256.f);
        float var = q * (1.f / 256.f) - mu * mu;
        sh_mu[tid] = mu;
        sh_rs[tid] = 1.f / sqrtf(var + 1e-5f);
    }
    __syncthreads();
    for (int i = tid; i < NN * DD1; i += 256) {
        int n = i >> 8, d = i & 255;
        sh_x[n][d] = ln_g[d] * (sh_x[n][d] - sh_mu[n]) * sh_rs[n] + ln_b[d];
    }
    __syncthreads();

    // ---- gi = x2ln @ W_ih + b_ih -------------------------------------------
    #pragma unroll
    for (int c = 0; c < 3; c++) {
        const int j = tid + c * 256;
        float acc[NN];
        float bj = b_ih[j];
        #pragma unroll
        for (int n = 0; n < NN; n++) acc[n] = bj;
        for (int k = 0; k < HIDD; k += 4) {
            float w0 = W_ih[(size_t)(k + 0) * G3 + j], w1 = W_ih[(size_t)(k + 1) * G3 + j];
            float w2 = W_ih[(size_t)(k + 2) * G3 + j], w3 = W_ih[(size_t)(k + 3) * G3 + j];
            #pragma unroll
            for (int n = 0; n < NN; n++) {
                float4 xv = *(const float4*)&sh_x[n][k];
                acc[n] = fmaf(xv.w, w3, fmaf(xv.z, w2, fmaf(xv.y, w1, fmaf(xv.x, w0, acc[n]))));
            }
        }
        #pragma unroll
        for (int n = 0; n < NN; n++)
            gi_out[(size_t)t * NN * G3 + n * G3 + j] = acc[n];
    }

    {
        float a = bf_[tid];
        #pragma unroll
        for (int k = 0; k < EEDD; k++) a += sev[k] * Wf[(size_t)(HIDD + k) * HIDD + tid];
        evc_out[(size_t)t * HIDD + tid] = a;
    }
}

// ---------------------------------------------------------------------------
// Kernel B: MFMA GRU scan. 1 block, 8 waves (2 waves/SIMD for latency hiding).
// W_hh held as bf16 B-fragments in registers (48 frags/wave = 192 regs).
// h double-buffered in LDS (hi/lo bf16 split) -> ONE barrier per step.
// Wave w owns gh/h columns [32w, 32w+32) for all three gates.
// ---------------------------------------------------------------------------
__global__ __launch_bounds__(512, 2) void scan_mfma_kernel(
    const float* __restrict__ gi, const float* __restrict__ W_hh,
    const float* __restrict__ b_hh, const float* __restrict__ hx,
    float* __restrict__ h_all)
{
    const int tid = threadIdx.x;
    const int w  = tid >> 6;       // wave 0..7
    const int l  = tid & 63;
    const int lc = l & 15;         // fragment col / A-row
    const int lg = l >> 4;         // k-group / C-row-group

    __shared__ short sh_hi[2][16 * HPAD];
    __shared__ short sh_lo[2][16 * HPAD];
    __shared__ float sgi[2][NN * G3];   // double-buffered gi(t); flat-aliased for W staging

    { // zero both h buffers (rows >= NN stay zero forever)
        short* p0 = &sh_hi[0][0];
        short* p1 = &sh_lo[0][0];
        for (int i = tid; i < 2 * 16 * HPAD; i += 512) { p0[i] = 0; p1[i] = 0; }
    }

    // ---- one-time: W_hh -> 48 bf16 B-frags per wave (staged via LDS) -------
    short8v wf[48];                 // [kk*6 + g*2 + f]
    float* wstage = &sgi[0][0];     // 12288-float scratch spanning both buffers
    for (int blk = 0; blk < 16; blk++) {
        __syncthreads();
        for (int i = tid; i < 16 * G3; i += 512)
            wstage[i] = W_hh[(size_t)(blk * 16) * G3 + i];
        __syncthreads();
        const int kk = blk >> 1, half = blk & 1;
        if ((lg >> 1) == half) {
            const int rbase = lg * 8 - half * 16;   // 0 or 8
            #pragma unroll
            for (int g = 0; g < 3; g++)
            #pragma unroll
            for (int f = 0; f < 2; f++) {
                const int col = g * 256 + w * 32 + f * 16 + lc;
                short8v v;
                #pragma unroll
                for (int j = 0; j < 8; j++)
                    v[j] = f2bf(wstage[(rbase + j) * G3 + col]);
                wf[kk * 6 + g * 2 + f] = v;
            }
        }
    }
    __syncthreads();   // all wstage reads done before gi(0) DMA overwrites sgi

    float bias[6];
    #pragma unroll
    for (int g = 0; g < 3; g++)
    #pragma unroll
    for (int f = 0; f < 2; f++)
        bias[g * 2 + f] = b_hh[g * 256 + w * 32 + f * 16 + lc];

    float hreg[8];   // [f*4+q]: h at (n = lg*4+q, u = w*32 + f*16 + lc)
    #pragma unroll
    for (int f = 0; f < 2; f++) {
        const int u = w * 32 + f * 16 + lc;
        #pragma unroll
        for (int q = 0; q < 4; q++) {
            const int n = lg * 4 + q;
            if (n < NN) {
                float h0 = hx[n * HIDD + u];
                hreg[f * 4 + q] = h0;
                short hi = f2bf(h0);
                sh_hi[0][n * HPAD + u] = hi;
                sh_lo[0][n * HPAD + u] = f2bf(h0 - bf2f(hi));
            }
        }
    }

    // prologue: prefetch gi(0) into buffer 0
    for (int c = w; c < 33; c += 8)
        gld16(gi + c * 256 + l * 4, &sgi[0][c * 256]);
    __syncthreads();   // vmcnt(0) drain at barrier -> gi(0) resident; h/zeros visible

    for (int t = 0; t < TT; t++) {
        const int pb = t & 1, nb = pb ^ 1;

        // prefetch gi(t+1) into the other buffer (drains at end-of-step barrier)
        if (t + 1 < TT) {
            const float* gsrc = gi + (size_t)(t + 1) * (NN * G3);
            for (int c = w; c < 33; c += 8)
                gld16(gsrc + c * 256 + l * 4, &sgi[nb][c * 256]);
        }

        // ---- gh = (h_hi + h_lo) @ W + b_hh via MFMA ------------------------
        const short* hbh = &sh_hi[pb][0];
        const short* hbl = &sh_lo[pb][0];
        float4v acc[6];
        #pragma unroll
        for (int j = 0; j < 6; j++)
            acc[j] = (float4v){bias[j], bias[j], bias[j], bias[j]};
        #pragma unroll
        for (int kk = 0; kk < 8; kk++) {
            const int ko = kk * 32 + lg * 8;
            short8v ahi = *(const short8v*)&hbh[lc * HPAD + ko];
            short8v alo = *(const short8v*)&hbl[lc * HPAD + ko];
            #pragma unroll
            for (int j = 0; j < 6; j++)
                acc[j] = __builtin_amdgcn_mfma_f32_16x16x32_bf16(ahi, wf[kk * 6 + j], acc[j], 0, 0, 0);
            #pragma unroll
            for (int j = 0; j < 6; j++)
                acc[j] = __builtin_amdgcn_mfma_f32_16x16x32_bf16(alo, wf[kk * 6 + j], acc[j], 0, 0, 0);
        }

        // ---- gates in registers; write h(t+1) into the OTHER buffer --------
        const float* gicur = &sgi[pb][0];
        short* nhi = &sh_hi[nb][0];
        short* nlo = &sh_lo[nb][0];
        #pragma unroll
        for (int f = 0; f < 2; f++) {
            const int u = w * 32 + f * 16 + lc;
            #pragma unroll
            for (int q = 0; q < 4; q++) {
                const int n = lg * 4 + q;
                if (n < NN) {
                    float gir = gicur[n * G3 + u];
                    float giz = gicur[n * G3 + 256 + u];
                    float gin = gicur[n * G3 + 512 + u];
                    float r   = sigm_f(gir + acc[f][q]);
                    float z   = sigm_f(giz + acc[2 + f][q]);
                    float nn_ = tanh_f(gin + r * acc[4 + f][q]);
                    float hnew = z * hreg[f * 4 + q] + (1.f - z) * nn_;
                    hreg[f * 4 + q] = hnew;
                    short hi = f2bf(hnew);
                    nhi[n * HPAD + u] = hi;
                    nlo[n * HPAD + u] = f2bf(hnew - bf2f(hi));
                    h_all[(size_t)t * (NN * HIDD) + n * HIDD + u] = hnew;
                }
            }
        }
        __syncthreads();   // h(t+1) + gi(t+1) ready for next step
    }
}

// ---------------------------------------------------------------------------
// Kernel C: time-parallel predictor head. One block per timestep.
// ---------------------------------------------------------------------------
__global__ __launch_bounds__(256) void predict_kernel(
    const float* __restrict__ h_all, const float* __restrict__ evc,
    const float* __restrict__ Wf, const float* __restrict__ Wp1,
    const float* __restrict__ bp1, const float* __restrict__ Wp2,
    const float* __restrict__ bp2, float* __restrict__ out)
{
    const int t = blockIdx.x, tid = threadIdx.x;
    __shared__ __align__(16) float sh[NN][HIDD];
    __shared__ __align__(16) float sf[NN][HIDD];
    __shared__ __align__(16) float sp[NN][128];
    __shared__ float red[176];

    for (int i = tid; i < NN * HIDD; i += 256)
        sh[i >> 8][i & 255] = h_all[(size_t)t * NN * HIDD + i];
    __syncthreads();
    {
        const int j = tid;
        float acc[NN];
        float e = evc[(size_t)t * HIDD + j];
        #pragma unroll
        for (int n = 0; n < NN; n++) acc[n] = e;
        for (int k = 0; k < HIDD; k += 4) {
            float w0 = Wf[(size_t)(k + 0) * HIDD + j], w1 = Wf[(size_t)(k + 1) * HIDD + j];
            float w2 = Wf[(size_t)(k + 2) * HIDD + j], w3 = Wf[(size_t)(k + 3) * HIDD + j];
            #pragma unroll
            for (int n = 0; n < NN; n++) {
                float4 hv = *(const float4*)&sh[n][k];
                acc[n] = fmaf(hv.w, w3, fmaf(hv.z, w2, fmaf(hv.y, w1, fmaf(hv.x, w0, acc[n]))));
            }
        }
        #pragma unroll
        for (int n = 0; n < NN; n++) sf[n][j] = fmaxf(acc[n], 0.f);
    }
    __syncthreads();
    if (tid < 128) {
        float acc[NN];
        float b = bp1[tid];
        #pragma unroll
        for (int n = 0; n < NN; n++) acc[n] = b;
        for (int k = 0; k < HIDD; k += 4) {
            float w0 = Wp1[(size_t)(k + 0) * 128 + tid], w1 = Wp1[(size_t)(k + 1) * 128 + tid];
            float w2 = Wp1[(size_t)(k + 2) * 128 + tid], w3 = Wp1[(size_t)(k + 3) * 128 + tid];
            #pragma unroll
            for (int n = 0; n < NN; n++) {
                float4 fv = *(const float4*)&sf[n][k];
                acc[n] = fmaf(fv.w, w3, fmaf(fv.z, w2, fmaf(fv.y, w1, fmaf(fv.x, w0, acc[n]))));
            }
        }
        #pragma unroll
        for (int n = 0; n < NN; n++) sp[n][tid] = fmaxf(acc[n], 0.f);
    }
    __syncthreads();
    if (tid < 176) {
        int n = tid >> 4, jj = tid & 15;
        float s = 0.f;
        for (int k = jj; k < 128; k += 16) s += sp[n][k] * Wp2[k];
        red[tid] = s;
    }
    __syncthreads();
    if (tid < NN) {
        float s = 0.f;
        #pragma unroll
        for (int j2 = 0; j2 < 16; j2++) s += red[tid * 16 + j2];
        out[(size_t)t * NN + tid] = s + bp2[0];
    }
}

// ---------------------------------------------------------------------------
extern "C" void kernel_launch(void* const* d_in, const int* in_sizes, int n_in,
                              void* d_out, int out_size, void* d_ws, size_t ws_size,
                              hipStream_t stream) {
    const float* x_in  = (const float*)d_in[0];
    const float* ea_in = (const float*)d_in[1];
    const float* evs   = (const float*)d_in[2];
    const float* hx    = (const float*)d_in[3];
    const int*   eidx  = (const int*)d_in[4];
    const float* W_np  = (const float*)d_in[5];
    const float* b_np  = (const float*)d_in[6];
    const float* bn_g  = (const float*)d_in[7];
    const float* bn_b  = (const float*)d_in[8];
    const float* We1   = (const float*)d_in[9];
    const float* be1   = (const float*)d_in[10];
    const float* We2   = (const float*)d_in[11];
    const float* be2   = (const float*)d_in[12];
    const float* Wg1   = (const float*)d_in[13];
    const float* bg1   = (const float*)d_in[14];
    const float* Wa1   = (const float*)d_in[15];
    const float* ba1   = (const float*)d_in[16];
    const float* Wg2   = (const float*)d_in[17];
    const float* bg2   = (const float*)d_in[18];
    const float* Wa2   = (const float*)d_in[19];
    const float* ba2   = (const float*)d_in[20];
    const float* ln_g  = (const float*)d_in[21];
    const float* ln_b  = (const float*)d_in[22];
    const float* W_ih  = (const float*)d_in[23];
    const float* W_hh  = (const float*)d_in[24];
    const float* b_ih  = (const float*)d_in[25];
    const float* b_hh  = (const float*)d_in[26];
    const float* Wf    = (const float*)d_in[27];
    const float* bf_   = (const float*)d_in[28];
    const float* Wp1   = (const float*)d_in[29];
    const float* bp1   = (const float*)d_in[30];
    const float* Wp2   = (const float*)d_in[31];
    const float* bp2   = (const float*)d_in[32];

    float* gi   = (float*)d_ws;                       // T*11*768
    float* evc  = gi  + (size_t)TT * NN * G3;         // T*256
    float* hall = evc + (size_t)TT * HIDD;            // T*11*256

    precompute_kernel<<<TT, 256, 0, stream>>>(
        x_in, ea_in, evs, eidx,
        W_np, b_np, bn_g, bn_b, We1, be1, We2, be2,
        Wg1, bg1, Wa1, ba1, Wg2, bg2, Wa2, ba2,
        ln_g, ln_b, W_ih, b_ih, Wf, bf_, gi, evc);

    scan_mfma_kernel<<<1, 512, 0, stream>>>(gi, W_hh, b_hh, hx, hall);

    predict_kernel<<<TT, 256, 0, stream>>>(
        hall, evc, Wf, Wp1, bp1, Wp2, bp2, (float*)d_out);
}

// Round 5
// 12125.169 us; speedup vs baseline: 2.0640x; 2.0640x over previous
//
#include <hip/hip_runtime.h>
#include <hip/hip_bf16.h>

#define TT   2048
#define NN   11
#define EE   110
#define NFD  5
#define EFD  4
#define HIDD 256
#define EEDD 32
#define DD1  256
#define G3   768
#define HPAD 264   // bf16 row stride for h in LDS

typedef __attribute__((ext_vector_type(8))) short short8v;
typedef __attribute__((ext_vector_type(4))) float float4v;

static __device__ inline short f2bf(float f) {
    union { __hip_bfloat16 b; short s; } u; u.b = __float2bfloat16(f); return u.s;
}
static __device__ inline float bf2f(short s) {
    union { short s; __hip_bfloat16 b; } u; u.s = s; return __bfloat162float(u.b);
}
static __device__ inline float sigm_f(float x) {
    return __builtin_amdgcn_rcpf(1.f + __builtin_amdgcn_exp2f(-1.4426950408889634f * x));
}
static __device__ inline float tanh_f(float x) {
    float e = __builtin_amdgcn_exp2f(2.8853900817779268f * x);   // exp(2x)
    return 1.f - 2.f * __builtin_amdgcn_rcpf(e + 1.f);
}
static __device__ inline void gld16(const float* g, float* s) {
    __builtin_amdgcn_global_load_lds((const __attribute__((address_space(1))) void*)g,
                                     (__attribute__((address_space(3))) void*)s, 16, 0, 0);
}

// ---------------------------------------------------------------------------
// Kernel A: time-parallel precompute. One block per timestep t.
// ---------------------------------------------------------------------------
__global__ __launch_bounds__(256) void precompute_kernel(
    const float* __restrict__ x, const float* __restrict__ edge_attr,
    const float* __restrict__ evs, const int* __restrict__ eidx,
    const float* __restrict__ W_np, const float* __restrict__ b_np,
    const float* __restrict__ bn_g, const float* __restrict__ bn_b,
    const float* __restrict__ We1, const float* __restrict__ be1,
    const float* __restrict__ We2, const float* __restrict__ be2,
    const float* __restrict__ Wg1, const float* __restrict__ bg1,
    const float* __restrict__ Wa1, const float* __restrict__ ba1,
    const float* __restrict__ Wg2, const float* __restrict__ bg2,
    const float* __restrict__ Wa2, const float* __restrict__ ba2,
    const float* __restrict__ ln_g, const float* __restrict__ ln_b,
    const float* __restrict__ W_ih, const float* __restrict__ b_ih,
    const float* __restrict__ Wf, const float* __restrict__ bf_,
    float* __restrict__ gi_out, float* __restrict__ evc_out)
{
    const int t   = blockIdx.x;
    const int tid = threadIdx.x;

    __shared__ __align__(16) float sh_h[NN][64];
    __shared__ __align__(16) float sh_e1[EE][32];
    __shared__ __align__(16) float sh_ea[EE][16];
    __shared__ __align__(16) float sh_h1[NN][DD1];
    __shared__ __align__(16) float sh_x[NN][DD1];
    __shared__ float sxt[NN * NFD];
    __shared__ float sev[EEDD];
    __shared__ float seat[EE * EFD];
    __shared__ float red[356];
    __shared__ float sh_s1[NN], sh_d1[NN];
    __shared__ float sh_elog[EE], sh_logit[EE], sh_alpha[EE];
    __shared__ float sh_mu[NN], sh_rs[NN];
    __shared__ float sredv[2];
    __shared__ int s_src[EE], s_dst[EE];
    __shared__ int cnt[NN], deg_start[NN + 1], e_by_dst[EE];

    if (tid < NN * NFD) sxt[tid] = x[(size_t)t * NN * NFD + tid];
    if (tid < EEDD)     sev[tid] = evs[(size_t)t * EEDD + tid];
    for (int i = tid; i < EE * EFD; i += 256)
        seat[i] = edge_attr[(size_t)t * EE * EFD + i];
    if (tid < EE) { s_src[tid] = eidx[tid]; s_dst[tid] = eidx[EE + tid]; }
    if (tid < NN) cnt[tid] = 0;
    __syncthreads();
    if (tid < EE) atomicAdd(&cnt[s_dst[tid]], 1);
    __syncthreads();
    if (tid == 0) {
        int a = 0;
        for (int n = 0; n < NN; n++) { deg_start[n] = a; a += cnt[n]; }
        deg_start[NN] = a;
    }
    __syncthreads();
    if (tid < NN) cnt[tid] = 0;
    __syncthreads();
    if (tid < EE) {
        int d = s_dst[tid];
        int pos = deg_start[d] + atomicAdd(&cnt[d], 1);
        e_by_dst[pos] = tid;
    }

    const float bn_inv = 1.0f / sqrtf(1.0f + 1e-5f);
    __syncthreads();
    for (int i = tid; i < NN * 64; i += 256) {
        int n = i >> 6, d = i & 63;
        float a = b_np[d];
        #pragma unroll
        for (int k = 0; k < NFD; k++) a += sxt[n * NFD + k] * W_np[k * 64 + d];
        a = fmaxf(a, 0.f);
        sh_h[n][d] = bn_g[d] * (a * bn_inv) + bn_b[d];
    }
    __syncthreads();

    for (int i = tid; i < EE * 32; i += 256) {
        int e = i >> 5, d = i & 31;
        float a = be1[d];
        #pragma unroll
        for (int k = 0; k < EFD; k++) a += seat[e * EFD + k] * We1[k * 32 + d];
        sh_e1[e][d] = fmaxf(a, 0.f);
    }
    __syncthreads();
    for (int i = tid; i < EE * 16; i += 256) {
        int e = i >> 4, d = i & 15;
        float a = be2[d];
        #pragma unroll
        for (int k = 0; k < 32; k++) a += sh_e1[e][k] * We2[k * 16 + d];
        sh_ea[e][d] = fmaxf(a, 0.f);
    }
    __syncthreads();

    // ======================= GAT layer 1 ====================================
    {
        const int j = tid;
        float acc[NN];
        #pragma unroll
        for (int n = 0; n < NN; n++) acc[n] = bg1[j];
        for (int k = 0; k < 64; k += 4) {
            float w0 = Wg1[(k + 0) * DD1 + j], w1 = Wg1[(k + 1) * DD1 + j];
            float w2 = Wg1[(k + 2) * DD1 + j], w3 = Wg1[(k + 3) * DD1 + j];
            #pragma unroll
            for (int n = 0; n < NN; n++) {
                float4 hv = *(const float4*)&sh_h[n][k];
                acc[n] = fmaf(hv.w, w3, fmaf(hv.z, w2, fmaf(hv.y, w1, fmaf(hv.x, w0, acc[n]))));
            }
        }
        #pragma unroll
        for (int n = 0; n < NN; n++) sh_h1[n][j] = acc[n];
    }
    __syncthreads();
    if (tid < EE) {
        float a = ba1[0];
        #pragma unroll
        for (int k = 0; k < 16; k++) a += sh_ea[tid][k] * Wa1[2 * DD1 + k];
        sh_elog[tid] = a;
    }
    if (tid < 176) {
        int g = tid >> 3, jj = tid & 7;
        int n = (g < NN) ? g : (g - NN);
        const float* wa = (g < NN) ? Wa1 : (Wa1 + DD1);
        float s = 0.f;
        for (int k = jj; k < DD1; k += 8) s += sh_h1[n][k] * wa[k];
        red[tid] = s;
    }
    __syncthreads();
    if (tid < 22) {
        float s = 0.f;
        #pragma unroll
        for (int j2 = 0; j2 < 8; j2++) s += red[tid * 8 + j2];
        if (tid < NN) sh_s1[tid] = s; else sh_d1[tid - NN] = s;
    }
    __syncthreads();
    if (tid < EE) sh_logit[tid] = sh_s1[s_src[tid]] + sh_d1[s_dst[tid]] + sh_elog[tid];
    __syncthreads();
    if (tid < 128) red[tid] = (tid < EE) ? sh_logit[tid] : -3.0e38f;
    __syncthreads();
    for (int s = 64; s > 0; s >>= 1) {
        if (tid < s) red[tid] = fmaxf(red[tid], red[tid + s]);
        __syncthreads();
    }
    if (tid == 0) sredv[0] = red[0];
    __syncthreads();
    if (tid < 128) {
        float v = (tid < EE) ? expf(sh_logit[tid] - sredv[0]) : 0.f;
        if (tid < EE) sh_alpha[tid] = v;
        red[tid] = v;
    }
    __syncthreads();
    for (int s = 64; s > 0; s >>= 1) {
        if (tid < s) red[tid] += red[tid + s];
        __syncthreads();
    }
    if (tid == 0) sredv[1] = 1.f / red[0];
    __syncthreads();
    if (tid < EE) sh_alpha[tid] *= sredv[1];
    __syncthreads();
    for (int i = tid; i < NN * DD1; i += 256) {
        int n = i >> 8, d = i & 255;
        float a = 0.f;
        for (int p = deg_start[n]; p < deg_start[n + 1]; p++) {
            int e = e_by_dst[p];
            a += sh_alpha[e] * sh_h1[s_src[e]][d];
        }
        sh_x[n][d] = fmaxf(a, 0.f);
    }
    __syncthreads();

    // ======================= GAT layer 2 ====================================
    {
        const int j = tid;
        float acc[NN];
        #pragma unroll
        for (int n = 0; n < NN; n++) acc[n] = bg2[j];
        for (int k = 0; k < DD1; k += 4) {
            float w0 = Wg2[(k + 0) * DD1 + j], w1 = Wg2[(k + 1) * DD1 + j];
            float w2 = Wg2[(k + 2) * DD1 + j], w3 = Wg2[(k + 3) * DD1 + j];
            #pragma unroll
            for (int n = 0; n < NN; n++) {
                float4 xv = *(const float4*)&sh_x[n][k];
                acc[n] = fmaf(xv.w, w3, fmaf(xv.z, w2, fmaf(xv.y, w1, fmaf(xv.x, w0, acc[n]))));
            }
        }
        #pragma unroll
        for (int n = 0; n < NN; n++) sh_h1[n][j] = acc[n];
    }
    __syncthreads();
    if (tid < EE) {
        float a = ba2[0];
        #pragma unroll
        for (int k = 0; k < 16; k++) a += sh_ea[tid][k] * Wa2[2 * DD1 + k];
        sh_elog[tid] = a;
    }
    if (tid < 176) {
        int g = tid >> 3, jj = tid & 7;
        int n = (g < NN) ? g : (g - NN);
        const float* wa = (g < NN) ? Wa2 : (Wa2 + DD1);
        float s = 0.f;
        for (int k = jj; k < DD1; k += 8) s += sh_h1[n][k] * wa[k];
        red[tid] = s;
    }
    __syncthreads();
    if (tid < 22) {
        float s = 0.f;
        #pragma unroll
        for (int j2 = 0; j2 < 8; j2++) s += red[tid * 8 + j2];
        if (tid < NN) sh_s1[tid] = s; else sh_d1[tid - NN] = s;
    }
    __syncthreads();
    if (tid < EE) sh_logit[tid] = sh_s1[s_src[tid]] + sh_d1[s_dst[tid]] + sh_elog[tid];
    __syncthreads();
    if (tid < 128) red[tid] = (tid < EE) ? sh_logit[tid] : -3.0e38f;
    __syncthreads();
    for (int s = 64; s > 0; s >>= 1) {
        if (tid < s) red[tid] = fmaxf(red[tid], red[tid + s]);
        __syncthreads();
    }
    if (tid == 0) sredv[0] = red[0];
    __syncthreads();
    if (tid < 128) {
        float v = (tid < EE) ? expf(sh_logit[tid] - sredv[0]) : 0.f;
        if (tid < EE) sh_alpha[tid] = v;
        red[tid] = v;
    }
    __syncthreads();
    for (int s = 64; s > 0; s >>= 1) {
        if (tid < s) red[tid] += red[tid + s];
        __syncthreads();
    }
    if (tid == 0) sredv[1] = 1.f / red[0];
    __syncthreads();
    if (tid < EE) sh_alpha[tid] *= sredv[1];
    __syncthreads();
    for (int i = tid; i < NN * DD1; i += 256) {
        int n = i >> 8, d = i & 255;
        float a = 0.f;
        for (int p = deg_start[n]; p < deg_start[n + 1]; p++) {
            int e = e_by_dst[p];
            a += sh_alpha[e] * sh_h1[s_src[e]][d];
        }
        sh_x[n][d] = fmaxf(a, 0.f);
    }
    __syncthreads();

    // ---- LayerNorm ---------------------------------------------------------
    if (tid < 176) {
        int n = tid >> 4, jj = tid & 15;
        float s = 0.f, q = 0.f;
        for (int k = jj; k < DD1; k += 16) {
            float v = sh_x[n][k];
            s += v; q += v * v;
        }
        red[tid] = s; red[176 + tid] = q;
    }
    __syncthreads();
    if (tid < NN) {
        float s = 0.f, q = 0.f;
        #pragma unroll
        for (int j2 = 0; j2 < 16; j2++) { s += red[tid * 16 + j2]; q += red[176 + tid * 16 + j2]; }
        float mu = s * (1.f / 256.f);
        float var = q * (1.f / 256.f) - mu * mu;
        sh_mu[tid] = mu;
        sh_rs[tid] = 1.f / sqrtf(var + 1e-5f);
    }
    __syncthreads();
    for (int i = tid; i < NN * DD1; i += 256) {
        int n = i >> 8, d = i & 255;
        sh_x[n][d] = ln_g[d] * (sh_x[n][d] - sh_mu[n]) * sh_rs[n] + ln_b[d];
    }
    __syncthreads();

    // ---- gi = x2ln @ W_ih + b_ih -------------------------------------------
    #pragma unroll
    for (int c = 0; c < 3; c++) {
        const int j = tid + c * 256;
        float acc[NN];
        float bj = b_ih[j];
        #pragma unroll
        for (int n = 0; n < NN; n++) acc[n] = bj;
        for (int k = 0; k < HIDD; k += 4) {
            float w0 = W_ih[(size_t)(k + 0) * G3 + j], w1 = W_ih[(size_t)(k + 1) * G3 + j];
            float w2 = W_ih[(size_t)(k + 2) * G3 + j], w3 = W_ih[(size_t)(k + 3) * G3 + j];
            #pragma unroll
            for (int n = 0; n < NN; n++) {
                float4 xv = *(const float4*)&sh_x[n][k];
                acc[n] = fmaf(xv.w, w3, fmaf(xv.z, w2, fmaf(xv.y, w1, fmaf(xv.x, w0, acc[n]))));
            }
        }
        #pragma unroll
        for (int n = 0; n < NN; n++)
            gi_out[(size_t)t * NN * G3 + n * G3 + j] = acc[n];
    }

    {
        float a = bf_[tid];
        #pragma unroll
        for (int k = 0; k < EEDD; k++) a += sev[k] * Wf[(size_t)(HIDD + k) * HIDD + tid];
        evc_out[(size_t)t * HIDD + tid] = a;
    }
}

// ---------------------------------------------------------------------------
// Kernel B: MFMA GRU scan. 1 block, 8 waves (2 waves/SIMD for latency hiding).
// W_hh held as bf16 B-fragments in registers (48 frags/wave = 192 regs).
// h double-buffered in LDS (hi/lo bf16 split) -> ONE barrier per step.
// Wave w owns gh/h columns [32w, 32w+32) for all three gates.
// NOTE: the W-load loop MUST be fully unrolled -- wf[] indices must be
// compile-time constants or the array is demoted to scratch (round-4 bug).
// ---------------------------------------------------------------------------
__global__ __launch_bounds__(512, 2) void scan_mfma_kernel(
    const float* __restrict__ gi, const float* __restrict__ W_hh,
    const float* __restrict__ b_hh, const float* __restrict__ hx,
    float* __restrict__ h_all)
{
    const int tid = threadIdx.x;
    const int w  = tid >> 6;       // wave 0..7
    const int l  = tid & 63;
    const int lc = l & 15;         // fragment col / A-row
    const int lg = l >> 4;         // k-group / C-row-group

    __shared__ short sh_hi[2][16 * HPAD];
    __shared__ short sh_lo[2][16 * HPAD];
    __shared__ float sgi[2][NN * G3];   // double-buffered gi(t); flat-aliased for W staging

    { // zero both h buffers (rows >= NN stay zero forever)
        short* p0 = &sh_hi[0][0];
        short* p1 = &sh_lo[0][0];
        for (int i = tid; i < 2 * 16 * HPAD; i += 512) { p0[i] = 0; p1[i] = 0; }
    }

    // ---- one-time: W_hh -> 48 bf16 B-frags per wave (staged via LDS) -------
    short8v wf[48];                 // [kk*6 + g*2 + f]
    float* wstage = &sgi[0][0];     // 12288-float scratch spanning both buffers
    #pragma unroll
    for (int blk = 0; blk < 16; blk++) {
        __syncthreads();
        for (int i = tid; i < 16 * G3; i += 512)
            wstage[i] = W_hh[(size_t)(blk * 16) * G3 + i];
        __syncthreads();
        const int kk = blk >> 1, half = blk & 1;
        if ((lg >> 1) == half) {
            const int rbase = lg * 8 - half * 16;   // 0 or 8
            #pragma unroll
            for (int g = 0; g < 3; g++)
            #pragma unroll
            for (int f = 0; f < 2; f++) {
                const int col = g * 256 + w * 32 + f * 16 + lc;
                short8v v;
                #pragma unroll
                for (int j = 0; j < 8; j++)
                    v[j] = f2bf(wstage[(rbase + j) * G3 + col]);
                wf[kk * 6 + g * 2 + f] = v;
            }
        }
    }
    __syncthreads();   // all wstage reads done before gi(0) DMA overwrites sgi

    float bias[6];
    #pragma unroll
    for (int g = 0; g < 3; g++)
    #pragma unroll
    for (int f = 0; f < 2; f++)
        bias[g * 2 + f] = b_hh[g * 256 + w * 32 + f * 16 + lc];

    float hreg[8];   // [f*4+q]: h at (n = lg*4+q, u = w*32 + f*16 + lc)
    #pragma unroll
    for (int f = 0; f < 2; f++) {
        const int u = w * 32 + f * 16 + lc;
        #pragma unroll
        for (int q = 0; q < 4; q++) {
            const int n = lg * 4 + q;
            if (n < NN) {
                float h0 = hx[n * HIDD + u];
                hreg[f * 4 + q] = h0;
                short hi = f2bf(h0);
                sh_hi[0][n * HPAD + u] = hi;
                sh_lo[0][n * HPAD + u] = f2bf(h0 - bf2f(hi));
            }
        }
    }

    // prologue: prefetch gi(0) into buffer 0
    for (int c = w; c < 33; c += 8)
        gld16(gi + c * 256 + l * 4, &sgi[0][c * 256]);
    __syncthreads();   // vmcnt(0) drain at barrier -> gi(0) resident; h/zeros visible

    for (int t = 0; t < TT; t++) {
        const int pb = t & 1, nb = pb ^ 1;

        // prefetch gi(t+1) into the other buffer (drains at end-of-step barrier)
        if (t + 1 < TT) {
            const float* gsrc = gi + (size_t)(t + 1) * (NN * G3);
            for (int c = w; c < 33; c += 8)
                gld16(gsrc + c * 256 + l * 4, &sgi[nb][c * 256]);
        }

        // ---- gh = (h_hi + h_lo) @ W + b_hh via MFMA ------------------------
        const short* hbh = &sh_hi[pb][0];
        const short* hbl = &sh_lo[pb][0];
        float4v acc[6];
        #pragma unroll
        for (int j = 0; j < 6; j++)
            acc[j] = (float4v){bias[j], bias[j], bias[j], bias[j]};
        #pragma unroll
        for (int kk = 0; kk < 8; kk++) {
            const int ko = kk * 32 + lg * 8;
            short8v ahi = *(const short8v*)&hbh[lc * HPAD + ko];
            short8v alo = *(const short8v*)&hbl[lc * HPAD + ko];
            #pragma unroll
            for (int j = 0; j < 6; j++)
                acc[j] = __builtin_amdgcn_mfma_f32_16x16x32_bf16(ahi, wf[kk * 6 + j], acc[j], 0, 0, 0);
            #pragma unroll
            for (int j = 0; j < 6; j++)
                acc[j] = __builtin_amdgcn_mfma_f32_16x16x32_bf16(alo, wf[kk * 6 + j], acc[j], 0, 0, 0);
        }

        // ---- gates in registers; write h(t+1) into the OTHER buffer --------
        const float* gicur = &sgi[pb][0];
        short* nhi = &sh_hi[nb][0];
        short* nlo = &sh_lo[nb][0];
        #pragma unroll
        for (int f = 0; f < 2; f++) {
            const int u = w * 32 + f * 16 + lc;
            #pragma unroll
            for (int q = 0; q < 4; q++) {
                const int n = lg * 4 + q;
                if (n < NN) {
                    float gir = gicur[n * G3 + u];
                    float giz = gicur[n * G3 + 256 + u];
                    float gin = gicur[n * G3 + 512 + u];
                    float r   = sigm_f(gir + acc[f][q]);
                    float z   = sigm_f(giz + acc[2 + f][q]);
                    float nn_ = tanh_f(gin + r * acc[4 + f][q]);
                    float hnew = z * hreg[f * 4 + q] + (1.f - z) * nn_;
                    hreg[f * 4 + q] = hnew;
                    short hi = f2bf(hnew);
                    nhi[n * HPAD + u] = hi;
                    nlo[n * HPAD + u] = f2bf(hnew - bf2f(hi));
                    h_all[(size_t)t * (NN * HIDD) + n * HIDD + u] = hnew;
                }
            }
        }
        __syncthreads();   // h(t+1) + gi(t+1) ready for next step
    }
}

// ---------------------------------------------------------------------------
// Kernel C: time-parallel predictor head. One block per timestep.
// ---------------------------------------------------------------------------
__global__ __launch_bounds__(256) void predict_kernel(
    const float* __restrict__ h_all, const float* __restrict__ evc,
    const float* __restrict__ Wf, const float* __restrict__ Wp1,
    const float* __restrict__ bp1, const float* __restrict__ Wp2,
    const float* __restrict__ bp2, float* __restrict__ out)
{
    const int t = blockIdx.x, tid = threadIdx.x;
    __shared__ __align__(16) float sh[NN][HIDD];
    __shared__ __align__(16) float sf[NN][HIDD];
    __shared__ __align__(16) float sp[NN][128];
    __shared__ float red[176];

    for (int i = tid; i < NN * HIDD; i += 256)
        sh[i >> 8][i & 255] = h_all[(size_t)t * NN * HIDD + i];
    __syncthreads();
    {
        const int j = tid;
        float acc[NN];
        float e = evc[(size_t)t * HIDD + j];
        #pragma unroll
        for (int n = 0; n < NN; n++) acc[n] = e;
        for (int k = 0; k < HIDD; k += 4) {
            float w0 = Wf[(size_t)(k + 0) * HIDD + j], w1 = Wf[(size_t)(k + 1) * HIDD + j];
            float w2 = Wf[(size_t)(k + 2) * HIDD + j], w3 = Wf[(size_t)(k + 3) * HIDD + j];
            #pragma unroll
            for (int n = 0; n < NN; n++) {
                float4 hv = *(const float4*)&sh[n][k];
                acc[n] = fmaf(hv.w, w3, fmaf(hv.z, w2, fmaf(hv.y, w1, fmaf(hv.x, w0, acc[n]))));
            }
        }
        #pragma unroll
        for (int n = 0; n < NN; n++) sf[n][j] = fmaxf(acc[n], 0.f);
    }
    __syncthreads();
    if (tid < 128) {
        float acc[NN];
        float b = bp1[tid];
        #pragma unroll
        for (int n = 0; n < NN; n++) acc[n] = b;
        for (int k = 0; k < HIDD; k += 4) {
            float w0 = Wp1[(size_t)(k + 0) * 128 + tid], w1 = Wp1[(size_t)(k + 1) * 128 + tid];
            float w2 = Wp1[(size_t)(k + 2) * 128 + tid], w3 = Wp1[(size_t)(k + 3) * 128 + tid];
            #pragma unroll
            for (int n = 0; n < NN; n++) {
                float4 fv = *(const float4*)&sf[n][k];
                acc[n] = fmaf(fv.w, w3, fmaf(fv.z, w2, fmaf(fv.y, w1, fmaf(fv.x, w0, acc[n]))));
            }
        }
        #pragma unroll
        for (int n = 0; n < NN; n++) sp[n][tid] = fmaxf(acc[n], 0.f);
    }
    __syncthreads();
    if (tid < 176) {
        int n = tid >> 4, jj = tid & 15;
        float s = 0.f;
        for (int k = jj; k < 128; k += 16) s += sp[n][k] * Wp2[k];
        red[tid] = s;
    }
    __syncthreads();
    if (tid < NN) {
        float s = 0.f;
        #pragma unroll
        for (int j2 = 0; j2 < 16; j2++) s += red[tid * 16 + j2];
        out[(size_t)t * NN + tid] = s + bp2[0];
    }
}

// ---------------------------------------------------------------------------
extern "C" void kernel_launch(void* const* d_in, const int* in_sizes, int n_in,
                              void* d_out, int out_size, void* d_ws, size_t ws_size,
                              hipStream_t stream) {
    const float* x_in  = (const float*)d_in[0];
    const float* ea_in = (const float*)d_in[1];
    const float* evs   = (const float*)d_in[2];
    const float* hx    = (const float*)d_in[3];
    const int*   eidx  = (const int*)d_in[4];
    const float* W_np  = (const float*)d_in[5];
    const float* b_np  = (const float*)d_in[6];
    const float* bn_g  = (const float*)d_in[7];
    const float* bn_b  = (const float*)d_in[8];
    const float* We1   = (const float*)d_in[9];
    const float* be1   = (const float*)d_in[10];
    const float* We2   = (const float*)d_in[11];
    const float* be2   = (const float*)d_in[12];
    const float* Wg1   = (const float*)d_in[13];
    const float* bg1   = (const float*)d_in[14];
    const float* Wa1   = (const float*)d_in[15];
    const float* ba1   = (const float*)d_in[16];
    const float* Wg2   = (const float*)d_in[17];
    const float* bg2   = (const float*)d_in[18];
    const float* Wa2   = (const float*)d_in[19];
    const float* ba2   = (const float*)d_in[20];
    const float* ln_g  = (const float*)d_in[21];
    const float* ln_b  = (const float*)d_in[22];
    const float* W_ih  = (const float*)d_in[23];
    const float* W_hh  = (const float*)d_in[24];
    const float* b_ih  = (const float*)d_in[25];
    const float* b_hh  = (const float*)d_in[26];
    const float* Wf    = (const float*)d_in[27];
    const float* bf_   = (const float*)d_in[28];
    const float* Wp1   = (const float*)d_in[29];
    const float* bp1   = (const float*)d_in[30];
    const float* Wp2   = (const float*)d_in[31];
    const float* bp2   = (const float*)d_in[32];

    float* gi   = (float*)d_ws;                       // T*11*768
    float* evc  = gi  + (size_t)TT * NN * G3;         // T*256
    float* hall = evc + (size_t)TT * HIDD;            // T*11*256

    precompute_kernel<<<TT, 256, 0, stream>>>(
        x_in, ea_in, evs, eidx,
        W_np, b_np, bn_g, bn_b, We1, be1, We2, be2,
        Wg1, bg1, Wa1, ba1, Wg2, bg2, Wa2, ba2,
        ln_g, ln_b, W_ih, b_ih, Wf, bf_, gi, evc);

    scan_mfma_kernel<<<1, 512, 0, stream>>>(gi, W_hh, b_hh, hx, hall);

    predict_kernel<<<TT, 256, 0, stream>>>(
        hall, evc, Wf, Wp1, bp1, Wp2, bp2, (float*)d_out);
}

// Round 6
// 11802.574 us; speedup vs baseline: 2.1204x; 1.0273x over previous
//
#include <hip/hip_runtime.h>
#include <hip/hip_bf16.h>
#include <hip/hip_fp16.h>

#define TT   2048
#define NN   11
#define EE   110
#define NFD  5
#define EFD  4
#define HIDD 256
#define EEDD 32
#define DD1  256
#define G3   768
#define HPAD 264   // bf16 row stride for h in LDS (shorts)
#define GIP  8704  // padded gi stride per step in halfs (17408 B = 17 x 1KB chunks)

typedef __attribute__((ext_vector_type(8))) short short8v;
typedef __attribute__((ext_vector_type(4))) float float4v;

static __device__ inline short f2bf(float f) {
    union { __hip_bfloat16 b; short s; } u; u.b = __float2bfloat16(f); return u.s;
}
static __device__ inline float bf2f(short s) {
    union { short s; __hip_bfloat16 b; } u; u.s = s; return __bfloat162float(u.b);
}
static __device__ inline unsigned short f2h(float x) {
    return __half_as_ushort(__float2half(x));   // RNE
}
static __device__ inline float h2f(unsigned short v) {
    return __half2float(__ushort_as_half(v));
}
static __device__ inline float sigm_f(float x) {
    return __builtin_amdgcn_rcpf(1.f + __builtin_amdgcn_exp2f(-1.4426950408889634f * x));
}
static __device__ inline float tanh_f(float x) {
    float e = __builtin_amdgcn_exp2f(2.8853900817779268f * x);   // exp(2x)
    return 1.f - 2.f * __builtin_amdgcn_rcpf(e + 1.f);
}
static __device__ inline void gld16(const void* g, void* s) {
    __builtin_amdgcn_global_load_lds((const __attribute__((address_space(1))) void*)g,
                                     (__attribute__((address_space(3))) void*)s, 16, 0, 0);
}

// ---------------------------------------------------------------------------
// Kernel A: time-parallel precompute. One block per timestep t.
// gi is written as fp16 (padded stride GIP) -- the scan is single-CU
// stream-bound, so gi bytes are the scan's critical resource.
// ---------------------------------------------------------------------------
__global__ __launch_bounds__(256) void precompute_kernel(
    const float* __restrict__ x, const float* __restrict__ edge_attr,
    const float* __restrict__ evs, const int* __restrict__ eidx,
    const float* __restrict__ W_np, const float* __restrict__ b_np,
    const float* __restrict__ bn_g, const float* __restrict__ bn_b,
    const float* __restrict__ We1, const float* __restrict__ be1,
    const float* __restrict__ We2, const float* __restrict__ be2,
    const float* __restrict__ Wg1, const float* __restrict__ bg1,
    const float* __restrict__ Wa1, const float* __restrict__ ba1,
    const float* __restrict__ Wg2, const float* __restrict__ bg2,
    const float* __restrict__ Wa2, const float* __restrict__ ba2,
    const float* __restrict__ ln_g, const float* __restrict__ ln_b,
    const float* __restrict__ W_ih, const float* __restrict__ b_ih,
    const float* __restrict__ Wf, const float* __restrict__ bf_,
    unsigned short* __restrict__ gi_out, float* __restrict__ evc_out)
{
    const int t   = blockIdx.x;
    const int tid = threadIdx.x;

    __shared__ __align__(16) float sh_h[NN][64];
    __shared__ __align__(16) float sh_e1[EE][32];
    __shared__ __align__(16) float sh_ea[EE][16];
    __shared__ __align__(16) float sh_h1[NN][DD1];
    __shared__ __align__(16) float sh_x[NN][DD1];
    __shared__ float sxt[NN * NFD];
    __shared__ float sev[EEDD];
    __shared__ float seat[EE * EFD];
    __shared__ float red[356];
    __shared__ float sh_s1[NN], sh_d1[NN];
    __shared__ float sh_elog[EE], sh_logit[EE], sh_alpha[EE];
    __shared__ float sh_mu[NN], sh_rs[NN];
    __shared__ float sredv[2];
    __shared__ int s_src[EE], s_dst[EE];
    __shared__ int cnt[NN], deg_start[NN + 1], e_by_dst[EE];

    if (tid < NN * NFD) sxt[tid] = x[(size_t)t * NN * NFD + tid];
    if (tid < EEDD)     sev[tid] = evs[(size_t)t * EEDD + tid];
    for (int i = tid; i < EE * EFD; i += 256)
        seat[i] = edge_attr[(size_t)t * EE * EFD + i];
    if (tid < EE) { s_src[tid] = eidx[tid]; s_dst[tid] = eidx[EE + tid]; }
    if (tid < NN) cnt[tid] = 0;
    __syncthreads();
    if (tid < EE) atomicAdd(&cnt[s_dst[tid]], 1);
    __syncthreads();
    if (tid == 0) {
        int a = 0;
        for (int n = 0; n < NN; n++) { deg_start[n] = a; a += cnt[n]; }
        deg_start[NN] = a;
    }
    __syncthreads();
    if (tid < NN) cnt[tid] = 0;
    __syncthreads();
    if (tid < EE) {
        int d = s_dst[tid];
        int pos = deg_start[d] + atomicAdd(&cnt[d], 1);
        e_by_dst[pos] = tid;
    }

    const float bn_inv = 1.0f / sqrtf(1.0f + 1e-5f);
    __syncthreads();
    for (int i = tid; i < NN * 64; i += 256) {
        int n = i >> 6, d = i & 63;
        float a = b_np[d];
        #pragma unroll
        for (int k = 0; k < NFD; k++) a += sxt[n * NFD + k] * W_np[k * 64 + d];
        a = fmaxf(a, 0.f);
        sh_h[n][d] = bn_g[d] * (a * bn_inv) + bn_b[d];
    }
    __syncthreads();

    for (int i = tid; i < EE * 32; i += 256) {
        int e = i >> 5, d = i & 31;
        float a = be1[d];
        #pragma unroll
        for (int k = 0; k < EFD; k++) a += seat[e * EFD + k] * We1[k * 32 + d];
        sh_e1[e][d] = fmaxf(a, 0.f);
    }
    __syncthreads();
    for (int i = tid; i < EE * 16; i += 256) {
        int e = i >> 4, d = i & 15;
        float a = be2[d];
        #pragma unroll
        for (int k = 0; k < 32; k++) a += sh_e1[e][k] * We2[k * 16 + d];
        sh_ea[e][d] = fmaxf(a, 0.f);
    }
    __syncthreads();

    // ======================= GAT layer 1 ====================================
    {
        const int j = tid;
        float acc[NN];
        #pragma unroll
        for (int n = 0; n < NN; n++) acc[n] = bg1[j];
        for (int k = 0; k < 64; k += 4) {
            float w0 = Wg1[(k + 0) * DD1 + j], w1 = Wg1[(k + 1) * DD1 + j];
            float w2 = Wg1[(k + 2) * DD1 + j], w3 = Wg1[(k + 3) * DD1 + j];
            #pragma unroll
            for (int n = 0; n < NN; n++) {
                float4 hv = *(const float4*)&sh_h[n][k];
                acc[n] = fmaf(hv.w, w3, fmaf(hv.z, w2, fmaf(hv.y, w1, fmaf(hv.x, w0, acc[n]))));
            }
        }
        #pragma unroll
        for (int n = 0; n < NN; n++) sh_h1[n][j] = acc[n];
    }
    __syncthreads();
    if (tid < EE) {
        float a = ba1[0];
        #pragma unroll
        for (int k = 0; k < 16; k++) a += sh_ea[tid][k] * Wa1[2 * DD1 + k];
        sh_elog[tid] = a;
    }
    if (tid < 176) {
        int g = tid >> 3, jj = tid & 7;
        int n = (g < NN) ? g : (g - NN);
        const float* wa = (g < NN) ? Wa1 : (Wa1 + DD1);
        float s = 0.f;
        for (int k = jj; k < DD1; k += 8) s += sh_h1[n][k] * wa[k];
        red[tid] = s;
    }
    __syncthreads();
    if (tid < 22) {
        float s = 0.f;
        #pragma unroll
        for (int j2 = 0; j2 < 8; j2++) s += red[tid * 8 + j2];
        if (tid < NN) sh_s1[tid] = s; else sh_d1[tid - NN] = s;
    }
    __syncthreads();
    if (tid < EE) sh_logit[tid] = sh_s1[s_src[tid]] + sh_d1[s_dst[tid]] + sh_elog[tid];
    __syncthreads();
    if (tid < 128) red[tid] = (tid < EE) ? sh_logit[tid] : -3.0e38f;
    __syncthreads();
    for (int s = 64; s > 0; s >>= 1) {
        if (tid < s) red[tid] = fmaxf(red[tid], red[tid + s]);
        __syncthreads();
    }
    if (tid == 0) sredv[0] = red[0];
    __syncthreads();
    if (tid < 128) {
        float v = (tid < EE) ? expf(sh_logit[tid] - sredv[0]) : 0.f;
        if (tid < EE) sh_alpha[tid] = v;
        red[tid] = v;
    }
    __syncthreads();
    for (int s = 64; s > 0; s >>= 1) {
        if (tid < s) red[tid] += red[tid + s];
        __syncthreads();
    }
    if (tid == 0) sredv[1] = 1.f / red[0];
    __syncthreads();
    if (tid < EE) sh_alpha[tid] *= sredv[1];
    __syncthreads();
    for (int i = tid; i < NN * DD1; i += 256) {
        int n = i >> 8, d = i & 255;
        float a = 0.f;
        for (int p = deg_start[n]; p < deg_start[n + 1]; p++) {
            int e = e_by_dst[p];
            a += sh_alpha[e] * sh_h1[s_src[e]][d];
        }
        sh_x[n][d] = fmaxf(a, 0.f);
    }
    __syncthreads();

    // ======================= GAT layer 2 ====================================
    {
        const int j = tid;
        float acc[NN];
        #pragma unroll
        for (int n = 0; n < NN; n++) acc[n] = bg2[j];
        for (int k = 0; k < DD1; k += 4) {
            float w0 = Wg2[(k + 0) * DD1 + j], w1 = Wg2[(k + 1) * DD1 + j];
            float w2 = Wg2[(k + 2) * DD1 + j], w3 = Wg2[(k + 3) * DD1 + j];
            #pragma unroll
            for (int n = 0; n < NN; n++) {
                float4 xv = *(const float4*)&sh_x[n][k];
                acc[n] = fmaf(xv.w, w3, fmaf(xv.z, w2, fmaf(xv.y, w1, fmaf(xv.x, w0, acc[n]))));
            }
        }
        #pragma unroll
        for (int n = 0; n < NN; n++) sh_h1[n][j] = acc[n];
    }
    __syncthreads();
    if (tid < EE) {
        float a = ba2[0];
        #pragma unroll
        for (int k = 0; k < 16; k++) a += sh_ea[tid][k] * Wa2[2 * DD1 + k];
        sh_elog[tid] = a;
    }
    if (tid < 176) {
        int g = tid >> 3, jj = tid & 7;
        int n = (g < NN) ? g : (g - NN);
        const float* wa = (g < NN) ? Wa2 : (Wa2 + DD1);
        float s = 0.f;
        for (int k = jj; k < DD1; k += 8) s += sh_h1[n][k] * wa[k];
        red[tid] = s;
    }
    __syncthreads();
    if (tid < 22) {
        float s = 0.f;
        #pragma unroll
        for (int j2 = 0; j2 < 8; j2++) s += red[tid * 8 + j2];
        if (tid < NN) sh_s1[tid] = s; else sh_d1[tid - NN] = s;
    }
    __syncthreads();
    if (tid < EE) sh_logit[tid] = sh_s1[s_src[tid]] + sh_d1[s_dst[tid]] + sh_elog[tid];
    __syncthreads();
    if (tid < 128) red[tid] = (tid < EE) ? sh_logit[tid] : -3.0e38f;
    __syncthreads();
    for (int s = 64; s > 0; s >>= 1) {
        if (tid < s) red[tid] = fmaxf(red[tid], red[tid + s]);
        __syncthreads();
    }
    if (tid == 0) sredv[0] = red[0];
    __syncthreads();
    if (tid < 128) {
        float v = (tid < EE) ? expf(sh_logit[tid] - sredv[0]) : 0.f;
        if (tid < EE) sh_alpha[tid] = v;
        red[tid] = v;
    }
    __syncthreads();
    for (int s = 64; s > 0; s >>= 1) {
        if (tid < s) red[tid] += red[tid + s];
        __syncthreads();
    }
    if (tid == 0) sredv[1] = 1.f / red[0];
    __syncthreads();
    if (tid < EE) sh_alpha[tid] *= sredv[1];
    __syncthreads();
    for (int i = tid; i < NN * DD1; i += 256) {
        int n = i >> 8, d = i & 255;
        float a = 0.f;
        for (int p = deg_start[n]; p < deg_start[n + 1]; p++) {
            int e = e_by_dst[p];
            a += sh_alpha[e] * sh_h1[s_src[e]][d];
        }
        sh_x[n][d] = fmaxf(a, 0.f);
    }
    __syncthreads();

    // ---- LayerNorm ---------------------------------------------------------
    if (tid < 176) {
        int n = tid >> 4, jj = tid & 15;
        float s = 0.f, q = 0.f;
        for (int k = jj; k < DD1; k += 16) {
            float v = sh_x[n][k];
            s += v; q += v * v;
        }
        red[tid] = s; red[176 + tid] = q;
    }
    __syncthreads();
    if (tid < NN) {
        float s = 0.f, q = 0.f;
        #pragma unroll
        for (int j2 = 0; j2 < 16; j2++) { s += red[tid * 16 + j2]; q += red[176 + tid * 16 + j2]; }
        float mu = s * (1.f / 256.f);
        float var = q * (1.f / 256.f) - mu * mu;
        sh_mu[tid] = mu;
        sh_rs[tid] = 1.f / sqrtf(var + 1e-5f);
    }
    __syncthreads();
    for (int i = tid; i < NN * DD1; i += 256) {
        int n = i >> 8, d = i & 255;
        sh_x[n][d] = ln_g[d] * (sh_x[n][d] - sh_mu[n]) * sh_rs[n] + ln_b[d];
    }
    __syncthreads();

    // ---- gi = x2ln @ W_ih + b_ih, stored fp16 at padded stride GIP ---------
    #pragma unroll
    for (int c = 0; c < 3; c++) {
        const int j = tid + c * 256;
        float acc[NN];
        float bj = b_ih[j];
        #pragma unroll
        for (int n = 0; n < NN; n++) acc[n] = bj;
        for (int k = 0; k < HIDD; k += 4) {
            float w0 = W_ih[(size_t)(k + 0) * G3 + j], w1 = W_ih[(size_t)(k + 1) * G3 + j];
            float w2 = W_ih[(size_t)(k + 2) * G3 + j], w3 = W_ih[(size_t)(k + 3) * G3 + j];
            #pragma unroll
            for (int n = 0; n < NN; n++) {
                float4 xv = *(const float4*)&sh_x[n][k];
                acc[n] = fmaf(xv.w, w3, fmaf(xv.z, w2, fmaf(xv.y, w1, fmaf(xv.x, w0, acc[n]))));
            }
        }
        #pragma unroll
        for (int n = 0; n < NN; n++)
            gi_out[(size_t)t * GIP + n * G3 + j] = f2h(acc[n]);
    }

    {
        float a = bf_[tid];
        #pragma unroll
        for (int k = 0; k < EEDD; k++) a += sev[k] * Wf[(size_t)(HIDD + k) * HIDD + tid];
        evc_out[(size_t)t * HIDD + tid] = a;
    }
}

// ---------------------------------------------------------------------------
// Kernel B: MFMA GRU scan. 1 block, 8 waves (2/SIMD). W_hh in bf16 register
// fragments (192 VGPR/wave). h double-buffered hi/lo bf16 in LDS. gi streamed
// as fp16 via global_load_lds double-buffer. Per-step barrier uses counted
// vmcnt(8): the 8 h_all stores never drain; only the gi DMA (oldest) must land.
// ---------------------------------------------------------------------------
__global__ __launch_bounds__(512, 2) void scan_mfma_kernel(
    const unsigned short* __restrict__ gi16, const float* __restrict__ W_hh,
    const float* __restrict__ b_hh, const float* __restrict__ hx,
    unsigned short* __restrict__ hall16)
{
    const int tid = threadIdx.x;
    const int w  = tid >> 6;       // wave 0..7
    const int l  = tid & 63;
    const int lc = l & 15;         // fragment col / A-row
    const int lg = l >> 4;         // k-group / C-row-group

    // smem carving: [0,16896) h_hi[2][4224] | [16896,33792) h_lo[2][4224]
    //               [33792,68608) sgi[2][GIP] halfs
    // W-staging scratch (49152 B) aliases the front before h/gi init.
    __shared__ __align__(16) char smem[68608];
    short* sh_hi = (short*)smem;
    short* sh_lo = (short*)(smem + 16896);
    unsigned short* sgi = (unsigned short*)(smem + 33792);
    float* wstage = (float*)smem;

    // ---- one-time: W_hh -> 48 bf16 B-frags per wave (staged via LDS) -------
    // MUST be fully unrolled: wf[] indices must be compile-time constants
    // (round-4 lesson: runtime index -> scratch demotion).
    short8v wf[48];                 // [kk*6 + g*2 + f]
    #pragma unroll
    for (int blk = 0; blk < 16; blk++) {
        __syncthreads();
        for (int i = tid; i < 16 * G3; i += 512)
            wstage[i] = W_hh[(size_t)(blk * 16) * G3 + i];
        __syncthreads();
        const int kk = blk >> 1, half = blk & 1;
        if ((lg >> 1) == half) {
            const int rbase = lg * 8 - half * 16;   // 0 or 8
            #pragma unroll
            for (int g = 0; g < 3; g++)
            #pragma unroll
            for (int f = 0; f < 2; f++) {
                const int col = g * 256 + w * 32 + f * 16 + lc;
                short8v v;
                #pragma unroll
                for (int j = 0; j < 8; j++)
                    v[j] = f2bf(wstage[(rbase + j) * G3 + col]);
                wf[kk * 6 + g * 2 + f] = v;
            }
        }
    }
    __syncthreads();   // all wstage reads done; smem now free for h/gi

    float bias[6];
    #pragma unroll
    for (int g = 0; g < 3; g++)
    #pragma unroll
    for (int f = 0; f < 2; f++)
        bias[g * 2 + f] = b_hh[g * 256 + w * 32 + f * 16 + lc];

    // zero both h buffers (pad rows >= NN stay zero forever)
    for (int i = tid; i < 2 * 16 * HPAD; i += 512) { sh_hi[i] = 0; sh_lo[i] = 0; }
    __syncthreads();

    float hreg[8];   // [f*4+q]: h at (n = lg*4+q, u = w*32 + f*16 + lc)
    #pragma unroll
    for (int f = 0; f < 2; f++) {
        const int u = w * 32 + f * 16 + lc;
        #pragma unroll
        for (int q = 0; q < 4; q++) {
            const int n = lg * 4 + q;
            if (n < NN) {
                float h0 = hx[n * HIDD + u];
                hreg[f * 4 + q] = h0;
                short hi = f2bf(h0);
                sh_hi[n * HPAD + u] = hi;
                sh_lo[n * HPAD + u] = f2bf(h0 - bf2f(hi));
            }
        }
    }

    // prologue: prefetch gi(0) into buffer 0 (17 x 1KB chunks)
    for (int c = w; c < 17; c += 8)
        gld16(gi16 + c * 512 + l * 8, sgi + c * 512);
    __syncthreads();   // full drain: gi(0) resident, h/zeros visible

    size_t hall_base = 0;
    for (int t = 0; t < TT; t++) {
        const int pb = t & 1, nb = pb ^ 1;

        // issue gi(t+1) DMA first (oldest vmem ops this step)
        if (t + 1 < TT) {
            const unsigned short* gsrc = gi16 + (size_t)(t + 1) * GIP;
            for (int c = w; c < 17; c += 8)
                gld16(gsrc + c * 512 + l * 8, sgi + nb * GIP + c * 512);
        }
        __builtin_amdgcn_sched_barrier(0);   // pin DMA issue before everything

        // ---- gh = (h_hi + h_lo) @ W + b_hh via MFMA ------------------------
        const short* hbh = sh_hi + pb * 16 * HPAD;
        const short* hbl = sh_lo + pb * 16 * HPAD;
        float4v acc[6];
        #pragma unroll
        for (int j = 0; j < 6; j++)
            acc[j] = (float4v){bias[j], bias[j], bias[j], bias[j]};
        __builtin_amdgcn_s_setprio(1);
        #pragma unroll
        for (int kk = 0; kk < 8; kk++) {
            const int ko = kk * 32 + lg * 8;
            short8v ahi = *(const short8v*)&hbh[lc * HPAD + ko];
            short8v alo = *(const short8v*)&hbl[lc * HPAD + ko];
            #pragma unroll
            for (int j = 0; j < 6; j++)
                acc[j] = __builtin_amdgcn_mfma_f32_16x16x32_bf16(ahi, wf[kk * 6 + j], acc[j], 0, 0, 0);
            #pragma unroll
            for (int j = 0; j < 6; j++)
                acc[j] = __builtin_amdgcn_mfma_f32_16x16x32_bf16(alo, wf[kk * 6 + j], acc[j], 0, 0, 0);
        }
        __builtin_amdgcn_s_setprio(0);

        // ---- gates in registers; write h(t+1) into the OTHER buffer --------
        const unsigned short* gic = sgi + pb * GIP;
        short* nhi = sh_hi + nb * 16 * HPAD;
        short* nlo = sh_lo + nb * 16 * HPAD;
        #pragma unroll
        for (int f = 0; f < 2; f++) {
            const int u = w * 32 + f * 16 + lc;
            #pragma unroll
            for (int q = 0; q < 4; q++) {
                const int n = lg * 4 + q;
                if (n < NN) {
                    float gir = h2f(gic[n * G3 + u]);
                    float giz = h2f(gic[n * G3 + 256 + u]);
                    float gin = h2f(gic[n * G3 + 512 + u]);
                    float r   = sigm_f(gir + acc[f][q]);
                    float z   = sigm_f(giz + acc[2 + f][q]);
                    float nn_ = tanh_f(gin + r * acc[4 + f][q]);
                    float hnew = z * hreg[f * 4 + q] + (1.f - z) * nn_;
                    hreg[f * 4 + q] = hnew;
                    short hi = f2bf(hnew);
                    nhi[n * HPAD + u] = hi;
                    nlo[n * HPAD + u] = f2bf(hnew - bf2f(hi));
                    hall16[hall_base + n * HIDD + u] = f2h(hnew);
                }
            }
        }

        // counted-vmcnt barrier: wait LDS writes + gi DMA (oldest); the 8
        // newest vmem ops (h_all stores) may stay in flight.
        asm volatile("s_waitcnt vmcnt(8) lgkmcnt(0)" ::: "memory");
        __builtin_amdgcn_s_barrier();
        __builtin_amdgcn_sched_barrier(0);

        hall_base += NN * HIDD;
    }
}

// ---------------------------------------------------------------------------
// Kernel C: time-parallel predictor head. One block per timestep. h_all fp16.
// ---------------------------------------------------------------------------
__global__ __launch_bounds__(256) void predict_kernel(
    const unsigned short* __restrict__ hall16, const float* __restrict__ evc,
    const float* __restrict__ Wf, const float* __restrict__ Wp1,
    const float* __restrict__ bp1, const float* __restrict__ Wp2,
    const float* __restrict__ bp2, float* __restrict__ out)
{
    const int t = blockIdx.x, tid = threadIdx.x;
    __shared__ __align__(16) float sh[NN][HIDD];
    __shared__ __align__(16) float sf[NN][HIDD];
    __shared__ __align__(16) float sp[NN][128];
    __shared__ float red[176];

    for (int i = tid; i < NN * HIDD; i += 256)
        sh[i >> 8][i & 255] = h2f(hall16[(size_t)t * NN * HIDD + i]);
    __syncthreads();
    {
        const int j = tid;
        float acc[NN];
        float e = evc[(size_t)t * HIDD + j];
        #pragma unroll
        for (int n = 0; n < NN; n++) acc[n] = e;
        for (int k = 0; k < HIDD; k += 4) {
            float w0 = Wf[(size_t)(k + 0) * HIDD + j], w1 = Wf[(size_t)(k + 1) * HIDD + j];
            float w2 = Wf[(size_t)(k + 2) * HIDD + j], w3 = Wf[(size_t)(k + 3) * HIDD + j];
            #pragma unroll
            for (int n = 0; n < NN; n++) {
                float4 hv = *(const float4*)&sh[n][k];
                acc[n] = fmaf(hv.w, w3, fmaf(hv.z, w2, fmaf(hv.y, w1, fmaf(hv.x, w0, acc[n]))));
            }
        }
        #pragma unroll
        for (int n = 0; n < NN; n++) sf[n][j] = fmaxf(acc[n], 0.f);
    }
    __syncthreads();
    if (tid < 128) {
        float acc[NN];
        float b = bp1[tid];
        #pragma unroll
        for (int n = 0; n < NN; n++) acc[n] = b;
        for (int k = 0; k < HIDD; k += 4) {
            float w0 = Wp1[(size_t)(k + 0) * 128 + tid], w1 = Wp1[(size_t)(k + 1) * 128 + tid];
            float w2 = Wp1[(size_t)(k + 2) * 128 + tid], w3 = Wp1[(size_t)(k + 3) * 128 + tid];
            #pragma unroll
            for (int n = 0; n < NN; n++) {
                float4 fv = *(const float4*)&sf[n][k];
                acc[n] = fmaf(fv.w, w3, fmaf(fv.z, w2, fmaf(fv.y, w1, fmaf(fv.x, w0, acc[n]))));
            }
        }
        #pragma unroll
        for (int n = 0; n < NN; n++) sp[n][tid] = fmaxf(acc[n], 0.f);
    }
    __syncthreads();
    if (tid < 176) {
        int n = tid >> 4, jj = tid & 15;
        float s = 0.f;
        for (int k = jj; k < 128; k += 16) s += sp[n][k] * Wp2[k];
        red[tid] = s;
    }
    __syncthreads();
    if (tid < NN) {
        float s = 0.f;
        #pragma unroll
        for (int j2 = 0; j2 < 16; j2++) s += red[tid * 16 + j2];
        out[(size_t)t * NN + tid] = s + bp2[0];
    }
}

// ---------------------------------------------------------------------------
extern "C" void kernel_launch(void* const* d_in, const int* in_sizes, int n_in,
                              void* d_out, int out_size, void* d_ws, size_t ws_size,
                              hipStream_t stream) {
    const float* x_in  = (const float*)d_in[0];
    const float* ea_in = (const float*)d_in[1];
    const float* evs   = (const float*)d_in[2];
    const float* hx    = (const float*)d_in[3];
    const int*   eidx  = (const int*)d_in[4];
    const float* W_np  = (const float*)d_in[5];
    const float* b_np  = (const float*)d_in[6];
    const float* bn_g  = (const float*)d_in[7];
    const float* bn_b  = (const float*)d_in[8];
    const float* We1   = (const float*)d_in[9];
    const float* be1   = (const float*)d_in[10];
    const float* We2   = (const float*)d_in[11];
    const float* be2   = (const float*)d_in[12];
    const float* Wg1   = (const float*)d_in[13];
    const float* bg1   = (const float*)d_in[14];
    const float* Wa1   = (const float*)d_in[15];
    const float* ba1   = (const float*)d_in[16];
    const float* Wg2   = (const float*)d_in[17];
    const float* bg2   = (const float*)d_in[18];
    const float* Wa2   = (const float*)d_in[19];
    const float* ba2   = (const float*)d_in[20];
    const float* ln_g  = (const float*)d_in[21];
    const float* ln_b  = (const float*)d_in[22];
    const float* W_ih  = (const float*)d_in[23];
    const float* W_hh  = (const float*)d_in[24];
    const float* b_ih  = (const float*)d_in[25];
    const float* b_hh  = (const float*)d_in[26];
    const float* Wf    = (const float*)d_in[27];
    const float* bf_   = (const float*)d_in[28];
    const float* Wp1   = (const float*)d_in[29];
    const float* bp1   = (const float*)d_in[30];
    const float* Wp2   = (const float*)d_in[31];
    const float* bp2   = (const float*)d_in[32];

    // ws layout: gi16 (T*GIP halfs = 35.7MB) | evc (T*256 f32 = 2MB)
    //            | hall16 (T*11*256 halfs = 11.5MB)   total ~49MB
    unsigned short* gi16 = (unsigned short*)d_ws;
    float* evc = (float*)((char*)d_ws + (size_t)TT * GIP * 2);
    unsigned short* hall16 = (unsigned short*)((char*)evc + (size_t)TT * HIDD * 4);

    precompute_kernel<<<TT, 256, 0, stream>>>(
        x_in, ea_in, evs, eidx,
        W_np, b_np, bn_g, bn_b, We1, be1, We2, be2,
        Wg1, bg1, Wa1, ba1, Wg2, bg2, Wa2, ba2,
        ln_g, ln_b, W_ih, b_ih, Wf, bf_, gi16, evc);

    scan_mfma_kernel<<<1, 512, 0, stream>>>(gi16, W_hh, b_hh, hx, hall16);

    predict_kernel<<<TT, 256, 0, stream>>>(
        hall16, evc, Wf, Wp1, bp1, Wp2, bp2, (float*)d_out);
}

// Round 7
// 11264.095 us; speedup vs baseline: 2.2218x; 1.0478x over previous
//
#include <hip/hip_runtime.h>
#include <hip/hip_bf16.h>
#include <hip/hip_fp16.h>

#define TT   2048
#define NN   11
#define EE   110
#define NFD  5
#define EFD  4
#define HIDD 256
#define EEDD 32
#define DD1  256
#define G3   768
#define HPAD 264    // bf16 row stride for h in LDS (shorts)
#define GPT  12288  // gi_perm halfs per step (512 threads x 24 halfs)

typedef __attribute__((ext_vector_type(8))) short short8v;
typedef __attribute__((ext_vector_type(8))) unsigned short ushort8v;
typedef __attribute__((ext_vector_type(4))) unsigned short ushort4v;
typedef __attribute__((ext_vector_type(4))) float float4v;

static __device__ inline short f2bf(float f) {
    union { __hip_bfloat16 b; short s; } u; u.b = __float2bfloat16(f); return u.s;
}
static __device__ inline float bf2f(short s) {
    union { short s; __hip_bfloat16 b; } u; u.s = s; return __bfloat162float(u.b);
}
static __device__ inline unsigned short f2h(float x) {
    return __half_as_ushort(__float2half(x));   // RNE
}
static __device__ inline float h2f(unsigned short v) {
    return __half2float(__ushort_as_half(v));
}
static __device__ inline float sigm_f(float x) {
    return __builtin_amdgcn_rcpf(1.f + __builtin_amdgcn_exp2f(-1.4426950408889634f * x));
}
static __device__ inline float tanh_f(float x) {
    float e = __builtin_amdgcn_exp2f(2.8853900817779268f * x);   // exp(2x)
    return 1.f - 2.f * __builtin_amdgcn_rcpf(e + 1.f);
}

// ---------------------------------------------------------------------------
// Kernel A: time-parallel precompute. One block per timestep t.
// gi is written fp16 in a SCAN-THREAD-PERMUTED layout: scan thread st reads
// its 24 gate pre-activations contiguously at gi_perm[t*GPT + st*24].
// Order within a thread: [gate g(0..2)][f(0..1)][q(0..3)].
// ---------------------------------------------------------------------------
__global__ __launch_bounds__(256) void precompute_kernel(
    const float* __restrict__ x, const float* __restrict__ edge_attr,
    const float* __restrict__ evs, const int* __restrict__ eidx,
    const float* __restrict__ W_np, const float* __restrict__ b_np,
    const float* __restrict__ bn_g, const float* __restrict__ bn_b,
    const float* __restrict__ We1, const float* __restrict__ be1,
    const float* __restrict__ We2, const float* __restrict__ be2,
    const float* __restrict__ Wg1, const float* __restrict__ bg1,
    const float* __restrict__ Wa1, const float* __restrict__ ba1,
    const float* __restrict__ Wg2, const float* __restrict__ bg2,
    const float* __restrict__ Wa2, const float* __restrict__ ba2,
    const float* __restrict__ ln_g, const float* __restrict__ ln_b,
    const float* __restrict__ W_ih, const float* __restrict__ b_ih,
    const float* __restrict__ Wf, const float* __restrict__ bf_,
    unsigned short* __restrict__ gi_out, float* __restrict__ evc_out)
{
    const int t   = blockIdx.x;
    const int tid = threadIdx.x;

    __shared__ __align__(16) float sh_h[NN][64];
    __shared__ __align__(16) float sh_e1[EE][32];
    __shared__ __align__(16) float sh_ea[EE][16];
    __shared__ __align__(16) float sh_h1[NN][DD1];
    __shared__ __align__(16) float sh_x[NN][DD1];
    __shared__ float sxt[NN * NFD];
    __shared__ float sev[EEDD];
    __shared__ float seat[EE * EFD];
    __shared__ float red[356];
    __shared__ float sh_s1[NN], sh_d1[NN];
    __shared__ float sh_elog[EE], sh_logit[EE], sh_alpha[EE];
    __shared__ float sh_mu[NN], sh_rs[NN];
    __shared__ float sredv[2];
    __shared__ int s_src[EE], s_dst[EE];
    __shared__ int cnt[NN], deg_start[NN + 1], e_by_dst[EE];

    if (tid < NN * NFD) sxt[tid] = x[(size_t)t * NN * NFD + tid];
    if (tid < EEDD)     sev[tid] = evs[(size_t)t * EEDD + tid];
    for (int i = tid; i < EE * EFD; i += 256)
        seat[i] = edge_attr[(size_t)t * EE * EFD + i];
    if (tid < EE) { s_src[tid] = eidx[tid]; s_dst[tid] = eidx[EE + tid]; }
    if (tid < NN) cnt[tid] = 0;
    __syncthreads();
    if (tid < EE) atomicAdd(&cnt[s_dst[tid]], 1);
    __syncthreads();
    if (tid == 0) {
        int a = 0;
        for (int n = 0; n < NN; n++) { deg_start[n] = a; a += cnt[n]; }
        deg_start[NN] = a;
    }
    __syncthreads();
    if (tid < NN) cnt[tid] = 0;
    __syncthreads();
    if (tid < EE) {
        int d = s_dst[tid];
        int pos = deg_start[d] + atomicAdd(&cnt[d], 1);
        e_by_dst[pos] = tid;
    }

    const float bn_inv = 1.0f / sqrtf(1.0f + 1e-5f);
    __syncthreads();
    for (int i = tid; i < NN * 64; i += 256) {
        int n = i >> 6, d = i & 63;
        float a = b_np[d];
        #pragma unroll
        for (int k = 0; k < NFD; k++) a += sxt[n * NFD + k] * W_np[k * 64 + d];
        a = fmaxf(a, 0.f);
        sh_h[n][d] = bn_g[d] * (a * bn_inv) + bn_b[d];
    }
    __syncthreads();

    for (int i = tid; i < EE * 32; i += 256) {
        int e = i >> 5, d = i & 31;
        float a = be1[d];
        #pragma unroll
        for (int k = 0; k < EFD; k++) a += seat[e * EFD + k] * We1[k * 32 + d];
        sh_e1[e][d] = fmaxf(a, 0.f);
    }
    __syncthreads();
    for (int i = tid; i < EE * 16; i += 256) {
        int e = i >> 4, d = i & 15;
        float a = be2[d];
        #pragma unroll
        for (int k = 0; k < 32; k++) a += sh_e1[e][k] * We2[k * 16 + d];
        sh_ea[e][d] = fmaxf(a, 0.f);
    }
    __syncthreads();

    // ======================= GAT layer 1 ====================================
    {
        const int j = tid;
        float acc[NN];
        #pragma unroll
        for (int n = 0; n < NN; n++) acc[n] = bg1[j];
        for (int k = 0; k < 64; k += 4) {
            float w0 = Wg1[(k + 0) * DD1 + j], w1 = Wg1[(k + 1) * DD1 + j];
            float w2 = Wg1[(k + 2) * DD1 + j], w3 = Wg1[(k + 3) * DD1 + j];
            #pragma unroll
            for (int n = 0; n < NN; n++) {
                float4 hv = *(const float4*)&sh_h[n][k];
                acc[n] = fmaf(hv.w, w3, fmaf(hv.z, w2, fmaf(hv.y, w1, fmaf(hv.x, w0, acc[n]))));
            }
        }
        #pragma unroll
        for (int n = 0; n < NN; n++) sh_h1[n][j] = acc[n];
    }
    __syncthreads();
    if (tid < EE) {
        float a = ba1[0];
        #pragma unroll
        for (int k = 0; k < 16; k++) a += sh_ea[tid][k] * Wa1[2 * DD1 + k];
        sh_elog[tid] = a;
    }
    if (tid < 176) {
        int g = tid >> 3, jj = tid & 7;
        int n = (g < NN) ? g : (g - NN);
        const float* wa = (g < NN) ? Wa1 : (Wa1 + DD1);
        float s = 0.f;
        for (int k = jj; k < DD1; k += 8) s += sh_h1[n][k] * wa[k];
        red[tid] = s;
    }
    __syncthreads();
    if (tid < 22) {
        float s = 0.f;
        #pragma unroll
        for (int j2 = 0; j2 < 8; j2++) s += red[tid * 8 + j2];
        if (tid < NN) sh_s1[tid] = s; else sh_d1[tid - NN] = s;
    }
    __syncthreads();
    if (tid < EE) sh_logit[tid] = sh_s1[s_src[tid]] + sh_d1[s_dst[tid]] + sh_elog[tid];
    __syncthreads();
    if (tid < 128) red[tid] = (tid < EE) ? sh_logit[tid] : -3.0e38f;
    __syncthreads();
    for (int s = 64; s > 0; s >>= 1) {
        if (tid < s) red[tid] = fmaxf(red[tid], red[tid + s]);
        __syncthreads();
    }
    if (tid == 0) sredv[0] = red[0];
    __syncthreads();
    if (tid < 128) {
        float v = (tid < EE) ? expf(sh_logit[tid] - sredv[0]) : 0.f;
        if (tid < EE) sh_alpha[tid] = v;
        red[tid] = v;
    }
    __syncthreads();
    for (int s = 64; s > 0; s >>= 1) {
        if (tid < s) red[tid] += red[tid + s];
        __syncthreads();
    }
    if (tid == 0) sredv[1] = 1.f / red[0];
    __syncthreads();
    if (tid < EE) sh_alpha[tid] *= sredv[1];
    __syncthreads();
    for (int i = tid; i < NN * DD1; i += 256) {
        int n = i >> 8, d = i & 255;
        float a = 0.f;
        for (int p = deg_start[n]; p < deg_start[n + 1]; p++) {
            int e = e_by_dst[p];
            a += sh_alpha[e] * sh_h1[s_src[e]][d];
        }
        sh_x[n][d] = fmaxf(a, 0.f);
    }
    __syncthreads();

    // ======================= GAT layer 2 ====================================
    {
        const int j = tid;
        float acc[NN];
        #pragma unroll
        for (int n = 0; n < NN; n++) acc[n] = bg2[j];
        for (int k = 0; k < DD1; k += 4) {
            float w0 = Wg2[(k + 0) * DD1 + j], w1 = Wg2[(k + 1) * DD1 + j];
            float w2 = Wg2[(k + 2) * DD1 + j], w3 = Wg2[(k + 3) * DD1 + j];
            #pragma unroll
            for (int n = 0; n < NN; n++) {
                float4 xv = *(const float4*)&sh_x[n][k];
                acc[n] = fmaf(xv.w, w3, fmaf(xv.z, w2, fmaf(xv.y, w1, fmaf(xv.x, w0, acc[n]))));
            }
        }
        #pragma unroll
        for (int n = 0; n < NN; n++) sh_h1[n][j] = acc[n];
    }
    __syncthreads();
    if (tid < EE) {
        float a = ba2[0];
        #pragma unroll
        for (int k = 0; k < 16; k++) a += sh_ea[tid][k] * Wa2[2 * DD1 + k];
        sh_elog[tid] = a;
    }
    if (tid < 176) {
        int g = tid >> 3, jj = tid & 7;
        int n = (g < NN) ? g : (g - NN);
        const float* wa = (g < NN) ? Wa2 : (Wa2 + DD1);
        float s = 0.f;
        for (int k = jj; k < DD1; k += 8) s += sh_h1[n][k] * wa[k];
        red[tid] = s;
    }
    __syncthreads();
    if (tid < 22) {
        float s = 0.f;
        #pragma unroll
        for (int j2 = 0; j2 < 8; j2++) s += red[tid * 8 + j2];
        if (tid < NN) sh_s1[tid] = s; else sh_d1[tid - NN] = s;
    }
    __syncthreads();
    if (tid < EE) sh_logit[tid] = sh_s1[s_src[tid]] + sh_d1[s_dst[tid]] + sh_elog[tid];
    __syncthreads();
    if (tid < 128) red[tid] = (tid < EE) ? sh_logit[tid] : -3.0e38f;
    __syncthreads();
    for (int s = 64; s > 0; s >>= 1) {
        if (tid < s) red[tid] = fmaxf(red[tid], red[tid + s]);
        __syncthreads();
    }
    if (tid == 0) sredv[0] = red[0];
    __syncthreads();
    if (tid < 128) {
        float v = (tid < EE) ? expf(sh_logit[tid] - sredv[0]) : 0.f;
        if (tid < EE) sh_alpha[tid] = v;
        red[tid] = v;
    }
    __syncthreads();
    for (int s = 64; s > 0; s >>= 1) {
        if (tid < s) red[tid] += red[tid + s];
        __syncthreads();
    }
    if (tid == 0) sredv[1] = 1.f / red[0];
    __syncthreads();
    if (tid < EE) sh_alpha[tid] *= sredv[1];
    __syncthreads();
    for (int i = tid; i < NN * DD1; i += 256) {
        int n = i >> 8, d = i & 255;
        float a = 0.f;
        for (int p = deg_start[n]; p < deg_start[n + 1]; p++) {
            int e = e_by_dst[p];
            a += sh_alpha[e] * sh_h1[s_src[e]][d];
        }
        sh_x[n][d] = fmaxf(a, 0.f);
    }
    __syncthreads();

    // ---- LayerNorm ---------------------------------------------------------
    if (tid < 176) {
        int n = tid >> 4, jj = tid & 15;
        float s = 0.f, q = 0.f;
        for (int k = jj; k < DD1; k += 16) {
            float v = sh_x[n][k];
            s += v; q += v * v;
        }
        red[tid] = s; red[176 + tid] = q;
    }
    __syncthreads();
    if (tid < NN) {
        float s = 0.f, q = 0.f;
        #pragma unroll
        for (int j2 = 0; j2 < 16; j2++) { s += red[tid * 16 + j2]; q += red[176 + tid * 16 + j2]; }
        float mu = s * (1.f / 256.f);
        float var = q * (1.f / 256.f) - mu * mu;
        sh_mu[tid] = mu;
        sh_rs[tid] = 1.f / sqrtf(var + 1e-5f);
    }
    __syncthreads();
    for (int i = tid; i < NN * DD1; i += 256) {
        int n = i >> 8, d = i & 255;
        sh_x[n][d] = ln_g[d] * (sh_x[n][d] - sh_mu[n]) * sh_rs[n] + ln_b[d];
    }
    __syncthreads();

    // ---- gi = x2ln @ W_ih + b_ih, written permuted fp16 --------------------
    // scan thread st = w*64 + lg*16 + lc consumes halfs [st*24 + g*8 + f*4 + q]
    // column j decodes as g=c, w=tid>>5, f=(tid>>4)&1, lc=tid&15; row n=lg*4+q.
    {
        const int wq  = tid >> 5;
        const int fq  = (tid >> 4) & 1;
        const int lcq = tid & 15;
        #pragma unroll
        for (int c = 0; c < 3; c++) {
            const int j = tid + c * 256;
            float acc[NN];
            float bj = b_ih[j];
            #pragma unroll
            for (int n = 0; n < NN; n++) acc[n] = bj;
            for (int k = 0; k < HIDD; k += 4) {
                float w0 = W_ih[(size_t)(k + 0) * G3 + j], w1 = W_ih[(size_t)(k + 1) * G3 + j];
                float w2 = W_ih[(size_t)(k + 2) * G3 + j], w3 = W_ih[(size_t)(k + 3) * G3 + j];
                #pragma unroll
                for (int n = 0; n < NN; n++) {
                    float4 xv = *(const float4*)&sh_x[n][k];
                    acc[n] = fmaf(xv.w, w3, fmaf(xv.z, w2, fmaf(xv.y, w1, fmaf(xv.x, w0, acc[n]))));
                }
            }
            #pragma unroll
            for (int lgq = 0; lgq < 3; lgq++) {
                ushort4v v4;
                #pragma unroll
                for (int q = 0; q < 4; q++) {
                    const int n = lgq * 4 + q;
                    v4[q] = (n < NN) ? f2h(acc[n < NN ? n : 0]) : (unsigned short)0;
                }
                const int st = wq * 64 + lgq * 16 + lcq;
                *(ushort4v*)(gi_out + (size_t)t * GPT + st * 24 + c * 8 + fq * 4) = v4;
            }
        }
    }

    {
        float a = bf_[tid];
        #pragma unroll
        for (int k = 0; k < EEDD; k++) a += sev[k] * Wf[(size_t)(HIDD + k) * HIDD + tid];
        evc_out[(size_t)t * HIDD + tid] = a;
    }
}

// ---------------------------------------------------------------------------
// Kernel B: MFMA GRU scan. 1 block, 8 waves (2/SIMD). W_hh in bf16 register
// fragments. h double-buffered hi/lo bf16 in LDS (separate arrays -- no
// aliasing). gi streamed via plain REGISTER loads from a thread-permuted
// layout: no global_load_lds, no LDS for gi, no compiler vmcnt serialization.
// Barrier = lgkmcnt(0) + s_barrier only.
// ---------------------------------------------------------------------------
__global__ __launch_bounds__(512, 2) void scan_mfma_kernel(
    const unsigned short* __restrict__ gip, const float* __restrict__ W_hh,
    const float* __restrict__ b_hh, const float* __restrict__ hx,
    unsigned short* __restrict__ hall16)
{
    const int tid = threadIdx.x;
    const int w  = tid >> 6;       // wave 0..7
    const int l  = tid & 63;
    const int lc = l & 15;         // fragment col / A-row
    const int lg = l >> 4;         // k-group / C-row-group

    __shared__ short sh_hi[2][16 * HPAD];
    __shared__ short sh_lo[2][16 * HPAD];
    __shared__ __align__(16) float wstage[16 * G3];

    // zero both h buffers (pad rows >= NN stay zero forever)
    {
        short* p0 = &sh_hi[0][0];
        short* p1 = &sh_lo[0][0];
        for (int i = tid; i < 2 * 16 * HPAD; i += 512) { p0[i] = 0; p1[i] = 0; }
    }

    // ---- one-time: W_hh -> 48 bf16 B-frags per wave (staged via LDS) -------
    // MUST be fully unrolled: wf[] indices must be compile-time constants.
    short8v wf[48];                 // [kk*6 + g*2 + f]
    #pragma unroll
    for (int blk = 0; blk < 16; blk++) {
        __syncthreads();
        for (int i = tid; i < 16 * G3; i += 512)
            wstage[i] = W_hh[(size_t)(blk * 16) * G3 + i];
        __syncthreads();
        const int kk = blk >> 1, half = blk & 1;
        if ((lg >> 1) == half) {
            const int rbase = lg * 8 - half * 16;   // 0 or 8
            #pragma unroll
            for (int g = 0; g < 3; g++)
            #pragma unroll
            for (int f = 0; f < 2; f++) {
                const int col = g * 256 + w * 32 + f * 16 + lc;
                short8v v;
                #pragma unroll
                for (int j = 0; j < 8; j++)
                    v[j] = f2bf(wstage[(rbase + j) * G3 + col]);
                wf[kk * 6 + g * 2 + f] = v;
            }
        }
    }

    float bias[6];
    #pragma unroll
    for (int g = 0; g < 3; g++)
    #pragma unroll
    for (int f = 0; f < 2; f++)
        bias[g * 2 + f] = b_hh[g * 256 + w * 32 + f * 16 + lc];

    float hreg[8];   // [f*4+q]: h at (n = lg*4+q, u = w*32 + f*16 + lc)
    #pragma unroll
    for (int f = 0; f < 2; f++) {
        const int u = w * 32 + f * 16 + lc;
        #pragma unroll
        for (int q = 0; q < 4; q++) {
            const int n = lg * 4 + q;
            if (n < NN) {
                float h0 = hx[n * HIDD + u];
                hreg[f * 4 + q] = h0;
                short hi = f2bf(h0);
                sh_hi[0][n * HPAD + u] = hi;
                sh_lo[0][n * HPAD + u] = f2bf(h0 - bf2f(hi));
            }
        }
    }
    __syncthreads();   // h(0) + zeros visible to all waves

    size_t hall_base = 0;
    for (int t = 0; t < TT; t++) {
        const int pb = t & 1, nb = pb ^ 1;

        // issue this step's gi register loads early (consumed in gates, so
        // the MFMA phase hides the HBM/L2 latency; compiler waits precisely
        // on these three loads, nothing else)
        const unsigned short* gp = gip + (size_t)t * GPT + tid * 24;
        ushort8v ga = *(const ushort8v*)(gp);
        ushort8v gb = *(const ushort8v*)(gp + 8);
        ushort8v gc = *(const ushort8v*)(gp + 16);

        // ---- gh = (h_hi + h_lo) @ W + b_hh via MFMA ------------------------
        const short* hbh = &sh_hi[pb][0];
        const short* hbl = &sh_lo[pb][0];
        float4v acc[6];
        #pragma unroll
        for (int j = 0; j < 6; j++)
            acc[j] = (float4v){bias[j], bias[j], bias[j], bias[j]};
        __builtin_amdgcn_s_setprio(1);
        #pragma unroll
        for (int kk = 0; kk < 8; kk++) {
            const int ko = kk * 32 + lg * 8;
            short8v ahi = *(const short8v*)&hbh[lc * HPAD + ko];
            short8v alo = *(const short8v*)&hbl[lc * HPAD + ko];
            #pragma unroll
            for (int j = 0; j < 6; j++)
                acc[j] = __builtin_amdgcn_mfma_f32_16x16x32_bf16(ahi, wf[kk * 6 + j], acc[j], 0, 0, 0);
            #pragma unroll
            for (int j = 0; j < 6; j++)
                acc[j] = __builtin_amdgcn_mfma_f32_16x16x32_bf16(alo, wf[kk * 6 + j], acc[j], 0, 0, 0);
        }
        __builtin_amdgcn_s_setprio(0);

        // ---- gates in registers; write h(t+1) into the OTHER buffer --------
        short* nhi = &sh_hi[nb][0];
        short* nlo = &sh_lo[nb][0];
        #pragma unroll
        for (int f = 0; f < 2; f++) {
            const int u = w * 32 + f * 16 + lc;
            #pragma unroll
            for (int q = 0; q < 4; q++) {
                const int n = lg * 4 + q;
                if (n < NN) {
                    float gir = h2f(ga[f * 4 + q]);
                    float giz = h2f(gb[f * 4 + q]);
                    float gin = h2f(gc[f * 4 + q]);
                    float r   = sigm_f(gir + acc[f][q]);
                    float z   = sigm_f(giz + acc[2 + f][q]);
                    float nn_ = tanh_f(gin + r * acc[4 + f][q]);
                    float hnew = z * hreg[f * 4 + q] + (1.f - z) * nn_;
                    hreg[f * 4 + q] = hnew;
                    short hi = f2bf(hnew);
                    nhi[n * HPAD + u] = hi;
                    nlo[n * HPAD + u] = f2bf(hnew - bf2f(hi));
                    hall16[hall_base + n * HIDD + u] = f2h(hnew);
                }
            }
        }

        // h ds_writes visible, then barrier; h_all stores never drained here
        asm volatile("s_waitcnt lgkmcnt(0)\n\ts_barrier" ::: "memory");
        hall_base += NN * HIDD;
    }
}

// ---------------------------------------------------------------------------
// Kernel C: time-parallel predictor head. One block per timestep. h_all fp16.
// ---------------------------------------------------------------------------
__global__ __launch_bounds__(256) void predict_kernel(
    const unsigned short* __restrict__ hall16, const float* __restrict__ evc,
    const float* __restrict__ Wf, const float* __restrict__ Wp1,
    const float* __restrict__ bp1, const float* __restrict__ Wp2,
    const float* __restrict__ bp2, float* __restrict__ out)
{
    const int t = blockIdx.x, tid = threadIdx.x;
    __shared__ __align__(16) float sh[NN][HIDD];
    __shared__ __align__(16) float sf[NN][HIDD];
    __shared__ __align__(16) float sp[NN][128];
    __shared__ float red[176];

    for (int i = tid; i < NN * HIDD; i += 256)
        sh[i >> 8][i & 255] = h2f(hall16[(size_t)t * NN * HIDD + i]);
    __syncthreads();
    {
        const int j = tid;
        float acc[NN];
        float e = evc[(size_t)t * HIDD + j];
        #pragma unroll
        for (int n = 0; n < NN; n++) acc[n] = e;
        for (int k = 0; k < HIDD; k += 4) {
            float w0 = Wf[(size_t)(k + 0) * HIDD + j], w1 = Wf[(size_t)(k + 1) * HIDD + j];
            float w2 = Wf[(size_t)(k + 2) * HIDD + j], w3 = Wf[(size_t)(k + 3) * HIDD + j];
            #pragma unroll
            for (int n = 0; n < NN; n++) {
                float4 hv = *(const float4*)&sh[n][k];
                acc[n] = fmaf(hv.w, w3, fmaf(hv.z, w2, fmaf(hv.y, w1, fmaf(hv.x, w0, acc[n]))));
            }
        }
        #pragma unroll
        for (int n = 0; n < NN; n++) sf[n][j] = fmaxf(acc[n], 0.f);
    }
    __syncthreads();
    if (tid < 128) {
        float acc[NN];
        float b = bp1[tid];
        #pragma unroll
        for (int n = 0; n < NN; n++) acc[n] = b;
        for (int k = 0; k < HIDD; k += 4) {
            float w0 = Wp1[(size_t)(k + 0) * 128 + tid], w1 = Wp1[(size_t)(k + 1) * 128 + tid];
            float w2 = Wp1[(size_t)(k + 2) * 128 + tid], w3 = Wp1[(size_t)(k + 3) * 128 + tid];
            #pragma unroll
            for (int n = 0; n < NN; n++) {
                float4 fv = *(const float4*)&sf[n][k];
                acc[n] = fmaf(fv.w, w3, fmaf(fv.z, w2, fmaf(fv.y, w1, fmaf(fv.x, w0, acc[n]))));
            }
        }
        #pragma unroll
        for (int n = 0; n < NN; n++) sp[n][tid] = fmaxf(acc[n], 0.f);
    }
    __syncthreads();
    if (tid < 176) {
        int n = tid >> 4, jj = tid & 15;
        float s = 0.f;
        for (int k = jj; k < 128; k += 16) s += sp[n][k] * Wp2[k];
        red[tid] = s;
    }
    __syncthreads();
    if (tid < NN) {
        float s = 0.f;
        #pragma unroll
        for (int j2 = 0; j2 < 16; j2++) s += red[tid * 16 + j2];
        out[(size_t)t * NN + tid] = s + bp2[0];
    }
}

// ---------------------------------------------------------------------------
extern "C" void kernel_launch(void* const* d_in, const int* in_sizes, int n_in,
                              void* d_out, int out_size, void* d_ws, size_t ws_size,
                              hipStream_t stream) {
    const float* x_in  = (const float*)d_in[0];
    const float* ea_in = (const float*)d_in[1];
    const float* evs   = (const float*)d_in[2];
    const float* hx    = (const float*)d_in[3];
    const int*   eidx  = (const int*)d_in[4];
    const float* W_np  = (const float*)d_in[5];
    const float* b_np  = (const float*)d_in[6];
    const float* bn_g  = (const float*)d_in[7];
    const float* bn_b  = (const float*)d_in[8];
    const float* We1   = (const float*)d_in[9];
    const float* be1   = (const float*)d_in[10];
    const float* We2   = (const float*)d_in[11];
    const float* be2   = (const float*)d_in[12];
    const float* Wg1   = (const float*)d_in[13];
    const float* bg1   = (const float*)d_in[14];
    const float* Wa1   = (const float*)d_in[15];
    const float* ba1   = (const float*)d_in[16];
    const float* Wg2   = (const float*)d_in[17];
    const float* bg2   = (const float*)d_in[18];
    const float* Wa2   = (const float*)d_in[19];
    const float* ba2   = (const float*)d_in[20];
    const float* ln_g  = (const float*)d_in[21];
    const float* ln_b  = (const float*)d_in[22];
    const float* W_ih  = (const float*)d_in[23];
    const float* W_hh  = (const float*)d_in[24];
    const float* b_ih  = (const float*)d_in[25];
    const float* b_hh  = (const float*)d_in[26];
    const float* Wf    = (const float*)d_in[27];
    const float* bf_   = (const float*)d_in[28];
    const float* Wp1   = (const float*)d_in[29];
    const float* bp1   = (const float*)d_in[30];
    const float* Wp2   = (const float*)d_in[31];
    const float* bp2   = (const float*)d_in[32];

    // ws layout: gi_perm (T*GPT halfs = 50.3MB) | evc (T*256 f32 = 2MB)
    //            | hall16 (T*11*256 halfs = 11.5MB)
    unsigned short* gip = (unsigned short*)d_ws;
    float* evc = (float*)((char*)d_ws + (size_t)TT * GPT * 2);
    unsigned short* hall16 = (unsigned short*)((char*)evc + (size_t)TT * HIDD * 4);

    precompute_kernel<<<TT, 256, 0, stream>>>(
        x_in, ea_in, evs, eidx,
        W_np, b_np, bn_g, bn_b, We1, be1, We2, be2,
        Wg1, bg1, Wa1, ba1, Wg2, bg2, Wa2, ba2,
        ln_g, ln_b, W_ih, b_ih, Wf, bf_, gip, evc);

    scan_mfma_kernel<<<1, 512, 0, stream>>>(gip, W_hh, b_hh, hx, hall16);

    predict_kernel<<<TT, 256, 0, stream>>>(
        hall16, evc, Wf, Wp1, bp1, Wp2, bp2, (float*)d_out);
}